// Round 1
// baseline (426.813 us; speedup 1.0000x reference)
//
#include <hip/hip_runtime.h>
#include <hip/hip_bf16.h>

typedef __bf16 bf16_t;
typedef bf16_t bf16x8 __attribute__((ext_vector_type(8)));
typedef float f32x4 __attribute__((ext_vector_type(4)));
typedef unsigned short u16;
typedef unsigned int u32;

static constexpr int kHW = 192 * 320;          // 61440
static constexpr float kC = 4.77464829275686f; // 30 / (2*pi)

__device__ __forceinline__ u16 f2bf(float f) {
  u32 u = __float_as_uint(f);
  return (u16)((u + 0x7FFFu + ((u >> 16) & 1u)) >> 16);
}

__device__ __forceinline__ u32 pack2(float a, float b) {
  __hip_bfloat162 h = __float22bfloat162_rn(make_float2(a, b));
  union { __hip_bfloat162 h2; u32 u; } cv;
  cv.h2 = h;
  return cv.u;
}

// LDS-visibility-only barrier: leaves global loads (weight prefetch) in flight.
__device__ __forceinline__ void lds_barrier() {
  __asm__ volatile("s_waitcnt lgkmcnt(0)\n\ts_barrier" ::: "memory");
}

// ---- d_ws layout ----
static constexpr int OFF_W0 = 0;        // [64][64] (t-col folded to bias)
static constexpr int OFF_W1 = 4096;     // [64][64]
static constexpr int OFF_W2 = 8192;     // [256][64]
static constexpr int OFF_W3 = 24576;    // [256][256]
static constexpr int OFF_W4 = 90112;    // [256][256]
static constexpr int OFF_W5 = 155648;   // [64][256] (not scaled)
static constexpr int W_TOTAL = 172032;
static constexpr int B_TOTAL = 1024;
static constexpr size_t FEAT_BYTE_OFF = 348160;
static constexpr size_t WS_NEED = FEAT_BYTE_OFF + (size_t)1920 * 8192;

__global__ void convert_weights(const float* __restrict__ w0, const float* __restrict__ w1,
                                const float* __restrict__ w2, const float* __restrict__ w3,
                                const float* __restrict__ w4, const float* __restrict__ w5,
                                const float* __restrict__ b0, const float* __restrict__ b1,
                                const float* __restrict__ b2, const float* __restrict__ b3,
                                const float* __restrict__ b4, const float* __restrict__ b5,
                                u16* __restrict__ wb, float* __restrict__ bws) {
  int i = blockIdx.x * 256 + threadIdx.x;
  if (i < W_TOTAL) {
    float v, s = kC;
    if (i < OFF_W1)      { int o = i >> 6, k = i & 63; v = w0[o * 65 + k]; }
    else if (i < OFF_W2) { v = w1[i - OFF_W1]; }
    else if (i < OFF_W3) { v = w2[i - OFF_W2]; }
    else if (i < OFF_W4) { v = w3[i - OFF_W3]; }
    else if (i < OFF_W5) { v = w4[i - OFF_W4]; }
    else                 { v = w5[i - OFF_W5]; s = 1.0f; }
    wb[i] = f2bf(v * s);
  } else {
    int j = i - W_TOTAL;
    float v;
    if (j < 64)       v = kC * b0[j];
    else if (j < 128) v = kC * w0[(j - 64) * 65 + 64];
    else if (j < 192) v = kC * b1[j - 128];
    else if (j < 448) v = kC * b2[j - 192];
    else if (j < 704) v = kC * b3[j - 448];
    else if (j < 960) v = kC * b4[j - 704];
    else              v = b5[j - 960];
    bws[j] = v;
  }
}

// Pre-transpose feat into the swizzled bf16 image (the exact L0 A-frag layout).
__global__ void convert_feat(const float* __restrict__ feat, u16* __restrict__ featT) {
  const int chunk = blockIdx.x;
  const int bq  = chunk / 960;
  const int hw0 = (chunk % 960) * 64;
  const int tid = threadIdx.x;
  const int p   = tid & 63;
  const int gg  = tid >> 6;
  const float* fbase = feat + (size_t)bq * 64 * kHW + hw0 + p;
  u16* img = featT + (size_t)chunk * 4096;
#pragma unroll
  for (int j = 0; j < 2; ++j) {
    const int g = gg * 2 + j;
    float v[8];
#pragma unroll
    for (int e = 0; e < 8; ++e) v[e] = fbase[(size_t)(g * 8 + e) * kHW];
    uint4 pk;
    pk.x = pack2(v[0], v[1]);
    pk.y = pack2(v[2], v[3]);
    pk.z = pack2(v[4], v[5]);
    pk.w = pack2(v[6], v[7]);
    *reinterpret_cast<uint4*>(img + p * 64 + ((g ^ (p & 7)) * 8)) = pk;
  }
}

template<int RSO>
__device__ __forceinline__ void epilogue_sin(f32x4 acc, u16* outb, int p, int g,
                                             int quad, int sw) {
  float s0 = __builtin_amdgcn_sinf(__builtin_amdgcn_fractf(acc[0]));
  float s1 = __builtin_amdgcn_sinf(__builtin_amdgcn_fractf(acc[1]));
  float s2 = __builtin_amdgcn_sinf(__builtin_amdgcn_fractf(acc[2]));
  float s3 = __builtin_amdgcn_sinf(__builtin_amdgcn_fractf(acc[3]));
  uint2 v;
  v.x = pack2(s0, s1);
  v.y = pack2(s2, s3);
  *reinterpret_cast<uint2*>(outb + p * RSO + ((g ^ sw) * 8) + (quad & 1) * 4) = v;
}

__device__ __forceinline__ f32x4 mf(bf16x8 a, bf16x8 b, f32x4 c) {
  return __builtin_amdgcn_mfma_f32_16x16x32_bf16(a, b, c, 0, 0, 0);
}

// 8-wave (512-thread) version: each wave owns 2 output tiles (32 rows) of the
// 256-wide layers -> per-wave weight fragments are 64 VGPRs (was 128), letting
// 4 waves/SIMD fit in the 128-reg budget. LDS stays 64 KB -> 2 blocks/CU ->
// 16 waves/CU (2x the previous occupancy).
template<bool PRE>
__global__ __attribute__((amdgpu_waves_per_eu(4, 4)))
void __launch_bounds__(512)
siren_main(const float* __restrict__ feat, const float* __restrict__ times,
           const u16* __restrict__ wb, const float* __restrict__ bws,
           const u16* __restrict__ featT, float* __restrict__ out) {
  __shared__ __align__(16) u16 A32[64 * 256];   // 32 KB
  __shared__ __align__(16) u16 B32[64 * 256];   // 32 KB
  u16* X = B32;         // 64x64 compact (stride 64), aliases B32 (dead by L3)
  u16* Y = B32 + 4096;

  const int tid   = threadIdx.x;
  const int bid   = blockIdx.x;
  const int c     = bid / 1920;
  const int chunk = bid % 1920;
  const int bq    = chunk / 960;
  const int hw0   = (chunk % 960) * 64;
  const float t   = times[c];
  const int wave  = tid >> 6;     // 0..7
  const int lane  = tid & 63;
  const int l15   = lane & 15;
  const int quad  = lane >> 4;
  const int sw    = l15 & 7;
  const int wlo   = wave & 3;     // col tile for 64-wide layers / L5
  const int whi   = wave >> 2;    // pixel-half selector for 64-wide layers / L5
  const int p0    = whi * 2;      // first pt of this wave's pixel pair

  // ---------- helpers ----------
  auto read_af8 = [&](bf16x8 (&af)[8], const u16* in, int pt) {
#pragma unroll
    for (int ks = 0; ks < 8; ++ks)
      af[ks] = *reinterpret_cast<const bf16x8*>(
          in + (pt * 16 + l15) * 256 + (((ks * 4 + quad) ^ sw) * 8));
  };
  auto read_af2 = [&](bf16x8 (&af)[2], const u16* in, int pt) {
#pragma unroll
    for (int ks = 0; ks < 2; ++ks)
      af[ks] = *reinterpret_cast<const bf16x8*>(
          in + (pt * 16 + l15) * 64 + (((ks * 4 + quad) ^ sw) * 8));
  };
  auto load_wf8 = [&](bf16x8 (&wf)[2][8], const u16* wbase) {
#pragma unroll
    for (int ot = 0; ot < 2; ++ot)
#pragma unroll
      for (int ks = 0; ks < 8; ++ks)
        wf[ot][ks] = *reinterpret_cast<const bf16x8*>(
            wbase + ((wave * 2 + ot) * 16 + l15) * 256 + ks * 32 + quad * 8);
  };
  auto load_bv2 = [&](f32x4 (&bv)[2], const float* bg) {
#pragma unroll
    for (int ot = 0; ot < 2; ++ot)
      bv[ot] = *reinterpret_cast<const f32x4*>(bg + (wave * 2 + ot) * 16 + quad * 4);
  };
  auto mfma_pt2 = [&](f32x4 (&acc)[2], bf16x8 (&wf)[2][8], bf16x8 (&af)[8],
                      const f32x4 (&bv)[2]) {
#pragma unroll
    for (int ot = 0; ot < 2; ++ot) acc[ot] = bv[ot];
#pragma unroll
    for (int ks = 0; ks < 8; ++ks)
#pragma unroll
      for (int ot = 0; ot < 2; ++ot)
        acc[ot] = mf(wf[ot][ks], af[ks], acc[ot]);
  };
  auto epi_pt2 = [&](f32x4 (&acc)[2], u16* outb, int pt) {
#pragma unroll
    for (int ot = 0; ot < 2; ++ot)
      epilogue_sin<256>(acc[ot], outb, pt * 16 + l15,
                        (wave * 2 + ot) * 2 + (quad >> 1), quad, sw);
  };

  // ---------- preload L0/L1 weights + biases (col tile = wlo) ----------
  bf16x8 wf0[2], wf1[2];
#pragma unroll
  for (int ks = 0; ks < 2; ++ks) {
    wf0[ks] = *reinterpret_cast<const bf16x8*>(wb + OFF_W0 + (wlo * 16 + l15) * 64 + ks * 32 + quad * 8);
    wf1[ks] = *reinterpret_cast<const bf16x8*>(wb + OFF_W1 + (wlo * 16 + l15) * 64 + ks * 32 + quad * 8);
  }
  f32x4 bv0, bv1;
  {
    f32x4 cb = *reinterpret_cast<const f32x4*>(bws + wlo * 16 + quad * 4);
    f32x4 cw = *reinterpret_cast<const f32x4*>(bws + 64 + wlo * 16 + quad * 4);
#pragma unroll
    for (int r = 0; r < 4; ++r) bv0[r] = cb[r] + t * cw[r];
    bv1 = *reinterpret_cast<const f32x4*>(bws + 128 + wlo * 16 + quad * 4);
  }

  bf16x8 wf2[2][2];
  f32x4  bv2[2];

  // ---------- L0: featT(global) or X(LDS) -> Y (wave handles pts p0, p0+1) ----------
  if constexpr (PRE) {
    const u16* fsrc = featT + (size_t)chunk * 4096;
    bf16x8 a0[2], a1[2];
#pragma unroll
    for (int ks = 0; ks < 2; ++ks) {
      a0[ks] = *reinterpret_cast<const bf16x8*>(
          fsrc + (p0 * 16 + l15) * 64 + (((ks * 4 + quad) ^ sw) * 8));
      a1[ks] = *reinterpret_cast<const bf16x8*>(
          fsrc + ((p0 + 1) * 16 + l15) * 64 + (((ks * 4 + quad) ^ sw) * 8));
    }
    // L2-layer weights: issue now, consumed two layers later
#pragma unroll
    for (int ot = 0; ot < 2; ++ot)
#pragma unroll
      for (int ks = 0; ks < 2; ++ks)
        wf2[ot][ks] = *reinterpret_cast<const bf16x8*>(
            wb + OFF_W2 + ((wave * 2 + ot) * 16 + l15) * 64 + ks * 32 + quad * 8);
    load_bv2(bv2, bws + 192);

    f32x4 acc;
    acc = bv0; acc = mf(wf0[0], a0[0], acc); acc = mf(wf0[1], a0[1], acc);
    epilogue_sin<64>(acc, Y, p0 * 16 + l15, wlo * 2 + (quad >> 1), quad, sw);
    acc = bv0; acc = mf(wf0[0], a1[0], acc); acc = mf(wf0[1], a1[1], acc);
    epilogue_sin<64>(acc, Y, (p0 + 1) * 16 + l15, wlo * 2 + (quad >> 1), quad, sw);
  } else {
    // fallback: stage into X, then classic LDS path (512 threads: 1 group each)
    {
      const int p  = tid & 63;
      const int g  = tid >> 6;   // 0..7
      const float* fbase = feat + (size_t)bq * 64 * kHW + hw0 + p;
      float v[8];
#pragma unroll
      for (int e = 0; e < 8; ++e) v[e] = fbase[(size_t)(g * 8 + e) * kHW];
      uint4 pk;
      pk.x = pack2(v[0], v[1]);
      pk.y = pack2(v[2], v[3]);
      pk.z = pack2(v[4], v[5]);
      pk.w = pack2(v[6], v[7]);
      *reinterpret_cast<uint4*>(X + p * 64 + ((g ^ (p & 7)) * 8)) = pk;
    }
    lds_barrier();
#pragma unroll
    for (int ot = 0; ot < 2; ++ot)
#pragma unroll
      for (int ks = 0; ks < 2; ++ks)
        wf2[ot][ks] = *reinterpret_cast<const bf16x8*>(
            wb + OFF_W2 + ((wave * 2 + ot) * 16 + l15) * 64 + ks * 32 + quad * 8);
    load_bv2(bv2, bws + 192);
#pragma unroll
    for (int i = 0; i < 2; ++i) {
      bf16x8 a[2];
      read_af2(a, X, p0 + i);
      f32x4 acc = bv0;
      acc = mf(wf0[0], a[0], acc); acc = mf(wf0[1], a[1], acc);
      epilogue_sin<64>(acc, Y, (p0 + i) * 16 + l15, wlo * 2 + (quad >> 1), quad, sw);
    }
  }
  lds_barrier();

  // ---------- L1: Y -> X (wave handles pts p0, p0+1) ----------
  {
    bf16x8 a0[2], a1[2];
    read_af2(a0, Y, p0);
    read_af2(a1, Y, p0 + 1);
    f32x4 acc;
    acc = bv1; acc = mf(wf1[0], a0[0], acc); acc = mf(wf1[1], a0[1], acc);
    epilogue_sin<64>(acc, X, p0 * 16 + l15, wlo * 2 + (quad >> 1), quad, sw);
    acc = bv1; acc = mf(wf1[0], a1[0], acc); acc = mf(wf1[1], a1[1], acc);
    epilogue_sin<64>(acc, X, (p0 + 1) * 16 + l15, wlo * 2 + (quad >> 1), quad, sw);
  }
  lds_barrier();

  // ---------- L2: X -> A32 (each wave: all 4 pts, 2 out tiles) ; tail-prefetch wf3 ----------
  bf16x8 wf3[2][8];
  f32x4  bv3[2];
  {
    bf16x8 a0[2], a1[2];
    read_af2(a0, X, 0);
    read_af2(a1, X, 1);
    {
      f32x4 acc[2];
#pragma unroll
      for (int ot = 0; ot < 2; ++ot) {
        acc[ot] = bv2[ot];
        acc[ot] = mf(wf2[ot][0], a0[0], acc[ot]);
        acc[ot] = mf(wf2[ot][1], a0[1], acc[ot]);
      }
      read_af2(a0, X, 2);
      epi_pt2(acc, A32, 0);
    }
    {
      f32x4 acc[2];
#pragma unroll
      for (int ot = 0; ot < 2; ++ot) {
        acc[ot] = bv2[ot];
        acc[ot] = mf(wf2[ot][0], a1[0], acc[ot]);
        acc[ot] = mf(wf2[ot][1], a1[1], acc[ot]);
      }
      read_af2(a1, X, 3);
      epi_pt2(acc, A32, 1);
    }
    {
      f32x4 acc[2];
#pragma unroll
      for (int ot = 0; ot < 2; ++ot) {
        acc[ot] = bv2[ot];
        acc[ot] = mf(wf2[ot][0], a0[0], acc[ot]);
        acc[ot] = mf(wf2[ot][1], a0[1], acc[ot]);
      }
      epi_pt2(acc, A32, 2);
    }
    {
      f32x4 acc[2];
#pragma unroll
      for (int ot = 0; ot < 2; ++ot) {
        acc[ot] = bv2[ot];
        acc[ot] = mf(wf2[ot][0], a1[0], acc[ot]);
        acc[ot] = mf(wf2[ot][1], a1[1], acc[ot]);
      }
      load_wf8(wf3, wb + OFF_W3);   // wf2 dead; weight loads fly over epi+barrier
      load_bv2(bv3, bws + 448);
      epi_pt2(acc, A32, 3);
    }
  }
  lds_barrier();

  // ---------- L3: A32 -> B32 ; tail-prefetch wf4 ----------
  bf16x8 wf4[2][8];
  f32x4  bv4[2];
  {
    bf16x8 af[8];
    f32x4 acc[2];
    read_af8(af, A32, 0);
    mfma_pt2(acc, wf3, af, bv3);
    read_af8(af, A32, 1);
    epi_pt2(acc, B32, 0);
    mfma_pt2(acc, wf3, af, bv3);
    read_af8(af, A32, 2);
    epi_pt2(acc, B32, 1);
    mfma_pt2(acc, wf3, af, bv3);
    read_af8(af, A32, 3);
    epi_pt2(acc, B32, 2);
    mfma_pt2(acc, wf3, af, bv3);
    load_wf8(wf4, wb + OFF_W4);     // wf3 dead after last MFMA: dests reuse its regs
    load_bv2(bv4, bws + 704);
    epi_pt2(acc, B32, 3);
  }
  lds_barrier();

  // ---------- L4: B32 -> A32 ; tail-prefetch wf5 ----------
  bf16x8 wf5[8];
  f32x4  bv5;
  {
    bf16x8 af[8];
    f32x4 acc[2];
    read_af8(af, B32, 0);
    mfma_pt2(acc, wf4, af, bv4);
    read_af8(af, B32, 1);
    epi_pt2(acc, A32, 0);
    mfma_pt2(acc, wf4, af, bv4);
    read_af8(af, B32, 2);
    epi_pt2(acc, A32, 1);
    mfma_pt2(acc, wf4, af, bv4);
    read_af8(af, B32, 3);
    epi_pt2(acc, A32, 2);
    mfma_pt2(acc, wf4, af, bv4);
#pragma unroll
    for (int ks = 0; ks < 8; ++ks)  // wf5: 32 regs (col tile = wlo)
      wf5[ks] = *reinterpret_cast<const bf16x8*>(
          wb + OFF_W5 + (wlo * 16 + l15) * 256 + ks * 32 + quad * 8);
    bv5 = *reinterpret_cast<const f32x4*>(bws + 960 + wlo * 16 + quad * 4);
    epi_pt2(acc, A32, 3);
  }
  lds_barrier();

  // ---------- L5: A32 -> global (wave: pts p0,p0+1; col tile wlo) ----------
  {
    float* out_base = out + (size_t)(c * 2 + bq) * 64 * kHW + hw0;
    bf16x8 af[8];
#pragma unroll
    for (int i = 0; i < 2; ++i) {
      const int pt = p0 + i;
      read_af8(af, A32, pt);
      f32x4 acc = bv5;
#pragma unroll
      for (int ks = 0; ks < 8; ++ks) acc = mf(wf5[ks], af[ks], acc);
      const int p = pt * 16 + l15;
      const int o = wlo * 16 + quad * 4;
      float* dst = out_base + (size_t)o * kHW + p;
#pragma unroll
      for (int r = 0; r < 4; ++r) dst[(size_t)r * kHW] = acc[r];
    }
  }
}

extern "C" void kernel_launch(void* const* d_in, const int* in_sizes, int n_in,
                              void* d_out, int out_size, void* d_ws, size_t ws_size,
                              hipStream_t stream) {
  const float* feat  = (const float*)d_in[0];
  const float* times = (const float*)d_in[1];
  const float* w0 = (const float*)d_in[2];
  const float* b0 = (const float*)d_in[3];
  const float* w1 = (const float*)d_in[4];
  const float* b1 = (const float*)d_in[5];
  const float* w2 = (const float*)d_in[6];
  const float* b2 = (const float*)d_in[7];
  const float* w3 = (const float*)d_in[8];
  const float* b3 = (const float*)d_in[9];
  const float* w4 = (const float*)d_in[10];
  const float* b4 = (const float*)d_in[11];
  const float* w5 = (const float*)d_in[12];
  const float* b5 = (const float*)d_in[13];
  u16*   wb  = (u16*)d_ws;
  float* bws = (float*)((char*)d_ws + (size_t)W_TOTAL * 2);
  float* out = (float*)d_out;

  convert_weights<<<(W_TOTAL + B_TOTAL) / 256, 256, 0, stream>>>(
      w0, w1, w2, w3, w4, w5, b0, b1, b2, b3, b4, b5, wb, bws);

  if (ws_size >= WS_NEED) {
    u16* featT = (u16*)((char*)d_ws + FEAT_BYTE_OFF);
    convert_feat<<<1920, 256, 0, stream>>>(feat, featT);
    siren_main<true><<<5760, 512, 0, stream>>>(feat, times, wb, bws, featT, out);
  } else {
    siren_main<false><<<5760, 512, 0, stream>>>(feat, times, wb, bws, wb, out);
  }
}

// Round 3
// 415.046 us; speedup vs baseline: 1.0284x; 1.0284x over previous
//
#include <hip/hip_runtime.h>
#include <hip/hip_bf16.h>

typedef __bf16 bf16_t;
typedef bf16_t bf16x8 __attribute__((ext_vector_type(8)));
typedef float f32x4 __attribute__((ext_vector_type(4)));
typedef unsigned short u16;
typedef unsigned int u32;

static constexpr int kHW = 192 * 320;          // 61440
static constexpr float kC = 4.77464829275686f; // 30 / (2*pi)

__device__ __forceinline__ u16 f2bf(float f) {
  u32 u = __float_as_uint(f);
  return (u16)((u + 0x7FFFu + ((u >> 16) & 1u)) >> 16);
}

__device__ __forceinline__ u32 pack2(float a, float b) {
  __hip_bfloat162 h = __float22bfloat162_rn(make_float2(a, b));
  union { __hip_bfloat162 h2; u32 u; } cv;
  cv.h2 = h;
  return cv.u;
}

// LDS-visibility-only barrier: leaves global loads (weight prefetch) in flight.
__device__ __forceinline__ void lds_barrier() {
  __asm__ volatile("s_waitcnt lgkmcnt(0)\n\ts_barrier" ::: "memory");
}

// ---- d_ws layout ----
static constexpr int OFF_W0 = 0;        // [64][64] (t-col folded to bias)
static constexpr int OFF_W1 = 4096;     // [64][64]
static constexpr int OFF_W2 = 8192;     // [256][64]
static constexpr int OFF_W3 = 24576;    // [256][256]
static constexpr int OFF_W4 = 90112;    // [256][256]
static constexpr int OFF_W5 = 155648;   // [64][256] (not scaled)
static constexpr int W_TOTAL = 172032;
static constexpr int B_TOTAL = 1024;
static constexpr size_t FEAT_BYTE_OFF = 348160;
static constexpr size_t WS_NEED = FEAT_BYTE_OFF + (size_t)1920 * 8192;

__global__ void convert_weights(const float* __restrict__ w0, const float* __restrict__ w1,
                                const float* __restrict__ w2, const float* __restrict__ w3,
                                const float* __restrict__ w4, const float* __restrict__ w5,
                                const float* __restrict__ b0, const float* __restrict__ b1,
                                const float* __restrict__ b2, const float* __restrict__ b3,
                                const float* __restrict__ b4, const float* __restrict__ b5,
                                u16* __restrict__ wb, float* __restrict__ bws) {
  int i = blockIdx.x * 256 + threadIdx.x;
  if (i < W_TOTAL) {
    float v, s = kC;
    if (i < OFF_W1)      { int o = i >> 6, k = i & 63; v = w0[o * 65 + k]; }
    else if (i < OFF_W2) { v = w1[i - OFF_W1]; }
    else if (i < OFF_W3) { v = w2[i - OFF_W2]; }
    else if (i < OFF_W4) { v = w3[i - OFF_W3]; }
    else if (i < OFF_W5) { v = w4[i - OFF_W4]; }
    else                 { v = w5[i - OFF_W5]; s = 1.0f; }
    wb[i] = f2bf(v * s);
  } else {
    int j = i - W_TOTAL;
    float v;
    if (j < 64)       v = kC * b0[j];
    else if (j < 128) v = kC * w0[(j - 64) * 65 + 64];
    else if (j < 192) v = kC * b1[j - 128];
    else if (j < 448) v = kC * b2[j - 192];
    else if (j < 704) v = kC * b3[j - 448];
    else if (j < 960) v = kC * b4[j - 704];
    else              v = b5[j - 960];
    bws[j] = v;
  }
}

// Pre-transpose feat into the swizzled bf16 image (the exact L0 A-frag layout).
__global__ void convert_feat(const float* __restrict__ feat, u16* __restrict__ featT) {
  const int chunk = blockIdx.x;
  const int bq  = chunk / 960;
  const int hw0 = (chunk % 960) * 64;
  const int tid = threadIdx.x;
  const int p   = tid & 63;
  const int gg  = tid >> 6;
  const float* fbase = feat + (size_t)bq * 64 * kHW + hw0 + p;
  u16* img = featT + (size_t)chunk * 4096;
#pragma unroll
  for (int j = 0; j < 2; ++j) {
    const int g = gg * 2 + j;
    float v[8];
#pragma unroll
    for (int e = 0; e < 8; ++e) v[e] = fbase[(size_t)(g * 8 + e) * kHW];
    uint4 pk;
    pk.x = pack2(v[0], v[1]);
    pk.y = pack2(v[2], v[3]);
    pk.z = pack2(v[4], v[5]);
    pk.w = pack2(v[6], v[7]);
    *reinterpret_cast<uint4*>(img + p * 64 + ((g ^ (p & 7)) * 8)) = pk;
  }
}

template<int RSO>
__device__ __forceinline__ void epilogue_sin(f32x4 acc, u16* outb, int p, int g,
                                             int quad, int sw) {
  float s0 = __builtin_amdgcn_sinf(__builtin_amdgcn_fractf(acc[0]));
  float s1 = __builtin_amdgcn_sinf(__builtin_amdgcn_fractf(acc[1]));
  float s2 = __builtin_amdgcn_sinf(__builtin_amdgcn_fractf(acc[2]));
  float s3 = __builtin_amdgcn_sinf(__builtin_amdgcn_fractf(acc[3]));
  uint2 v;
  v.x = pack2(s0, s1);
  v.y = pack2(s2, s3);
  *reinterpret_cast<uint2*>(outb + p * RSO + ((g ^ sw) * 8) + (quad & 1) * 4) = v;
}

__device__ __forceinline__ f32x4 mf(bf16x8 a, bf16x8 b, f32x4 c) {
  return __builtin_amdgcn_mfma_f32_16x16x32_bf16(a, b, c, 0, 0, 0);
}

// 8-wave (512-thread): per-wave weight fragments are 64 VGPRs; weight prefetch
// is half-split across layer boundaries (32 regs in flight) and pinned with
// sched_barrier so the scheduler cannot hoist it into the previous layer's
// weight live-range (that hoist caused the R1 spill: 208GB WRITE_SIZE).
template<bool PRE>
__global__ __attribute__((amdgpu_waves_per_eu(4, 4)))
void __launch_bounds__(512)
siren_main(const float* __restrict__ feat, const float* __restrict__ times,
           const u16* __restrict__ wb, const float* __restrict__ bws,
           const u16* __restrict__ featT, float* __restrict__ out) {
  __shared__ __align__(16) u16 A32[64 * 256];   // 32 KB
  __shared__ __align__(16) u16 B32[64 * 256];   // 32 KB
  u16* X = B32;         // 64x64 compact (stride 64), aliases B32 (dead by L3)
  u16* Y = B32 + 4096;

  const int tid   = threadIdx.x;
  const int bid   = blockIdx.x;
  const int c     = bid / 1920;
  const int chunk = bid % 1920;
  const int bq    = chunk / 960;
  const int hw0   = (chunk % 960) * 64;
  const float t   = times[c];
  const int wave  = tid >> 6;     // 0..7
  const int lane  = tid & 63;
  const int l15   = lane & 15;
  const int quad  = lane >> 4;
  const int sw    = l15 & 7;
  const int wlo   = wave & 3;     // col tile for 64-wide layers / L5
  const int whi   = wave >> 2;    // pixel-half selector for 64-wide layers / L5
  const int p0    = whi * 2;      // first pt of this wave's pixel pair

  // ---------- helpers ----------
  auto read_af8 = [&](bf16x8 (&af)[8], const u16* in, int pt) {
#pragma unroll
    for (int ks = 0; ks < 8; ++ks)
      af[ks] = *reinterpret_cast<const bf16x8*>(
          in + (pt * 16 + l15) * 256 + (((ks * 4 + quad) ^ sw) * 8));
  };
  auto read_af2 = [&](bf16x8 (&af)[2], const u16* in, int pt) {
#pragma unroll
    for (int ks = 0; ks < 2; ++ks)
      af[ks] = *reinterpret_cast<const bf16x8*>(
          in + (pt * 16 + l15) * 64 + (((ks * 4 + quad) ^ sw) * 8));
  };
  auto load_wf8 = [&](bf16x8 (&wf)[2][8], const u16* wbase) {
#pragma unroll
    for (int ot = 0; ot < 2; ++ot)
#pragma unroll
      for (int ks = 0; ks < 8; ++ks)
        wf[ot][ks] = *reinterpret_cast<const bf16x8*>(
            wbase + ((wave * 2 + ot) * 16 + l15) * 256 + ks * 32 + quad * 8);
  };
  auto load_wf8_ot = [&](bf16x8 (&wf)[2][8], const u16* wbase, int ot) {
#pragma unroll
    for (int ks = 0; ks < 8; ++ks)
      wf[ot][ks] = *reinterpret_cast<const bf16x8*>(
          wbase + ((wave * 2 + ot) * 16 + l15) * 256 + ks * 32 + quad * 8);
  };
  auto load_bv2 = [&](f32x4 (&bv)[2], const float* bg) {
#pragma unroll
    for (int ot = 0; ot < 2; ++ot)
      bv[ot] = *reinterpret_cast<const f32x4*>(bg + (wave * 2 + ot) * 16 + quad * 4);
  };
  auto mfma_pt2 = [&](f32x4 (&acc)[2], bf16x8 (&wf)[2][8], bf16x8 (&af)[8],
                      const f32x4 (&bv)[2]) {
#pragma unroll
    for (int ot = 0; ot < 2; ++ot) acc[ot] = bv[ot];
#pragma unroll
    for (int ks = 0; ks < 8; ++ks)
#pragma unroll
      for (int ot = 0; ot < 2; ++ot)
        acc[ot] = mf(wf[ot][ks], af[ks], acc[ot]);
  };
  auto epi_pt2 = [&](f32x4 (&acc)[2], u16* outb, int pt) {
#pragma unroll
    for (int ot = 0; ot < 2; ++ot)
      epilogue_sin<256>(acc[ot], outb, pt * 16 + l15,
                        (wave * 2 + ot) * 2 + (quad >> 1), quad, sw);
  };

  // ---------- preload L0/L1 weights + biases (col tile = wlo) ----------
  bf16x8 wf0[2], wf1[2];
#pragma unroll
  for (int ks = 0; ks < 2; ++ks) {
    wf0[ks] = *reinterpret_cast<const bf16x8*>(wb + OFF_W0 + (wlo * 16 + l15) * 64 + ks * 32 + quad * 8);
    wf1[ks] = *reinterpret_cast<const bf16x8*>(wb + OFF_W1 + (wlo * 16 + l15) * 64 + ks * 32 + quad * 8);
  }
  f32x4 bv0, bv1;
  {
    f32x4 cb = *reinterpret_cast<const f32x4*>(bws + wlo * 16 + quad * 4);
    f32x4 cw = *reinterpret_cast<const f32x4*>(bws + 64 + wlo * 16 + quad * 4);
#pragma unroll
    for (int r = 0; r < 4; ++r) bv0[r] = cb[r] + t * cw[r];
    bv1 = *reinterpret_cast<const f32x4*>(bws + 128 + wlo * 16 + quad * 4);
  }

  bf16x8 wf2[2][2];
  f32x4  bv2[2];

  // ---------- L0: featT(global) or X(LDS) -> Y (wave handles pts p0, p0+1) ----------
  if constexpr (PRE) {
    const u16* fsrc = featT + (size_t)chunk * 4096;
    bf16x8 a0[2], a1[2];
#pragma unroll
    for (int ks = 0; ks < 2; ++ks) {
      a0[ks] = *reinterpret_cast<const bf16x8*>(
          fsrc + (p0 * 16 + l15) * 64 + (((ks * 4 + quad) ^ sw) * 8));
      a1[ks] = *reinterpret_cast<const bf16x8*>(
          fsrc + ((p0 + 1) * 16 + l15) * 64 + (((ks * 4 + quad) ^ sw) * 8));
    }
    // L2-layer weights: issue now, consumed two layers later (only 8 regs)
#pragma unroll
    for (int ot = 0; ot < 2; ++ot)
#pragma unroll
      for (int ks = 0; ks < 2; ++ks)
        wf2[ot][ks] = *reinterpret_cast<const bf16x8*>(
            wb + OFF_W2 + ((wave * 2 + ot) * 16 + l15) * 64 + ks * 32 + quad * 8);
    load_bv2(bv2, bws + 192);

    f32x4 acc;
    acc = bv0; acc = mf(wf0[0], a0[0], acc); acc = mf(wf0[1], a0[1], acc);
    epilogue_sin<64>(acc, Y, p0 * 16 + l15, wlo * 2 + (quad >> 1), quad, sw);
    acc = bv0; acc = mf(wf0[0], a1[0], acc); acc = mf(wf0[1], a1[1], acc);
    epilogue_sin<64>(acc, Y, (p0 + 1) * 16 + l15, wlo * 2 + (quad >> 1), quad, sw);
  } else {
    // fallback: stage into X, then classic LDS path (512 threads: 1 group each)
    {
      const int p  = tid & 63;
      const int g  = tid >> 6;   // 0..7
      const float* fbase = feat + (size_t)bq * 64 * kHW + hw0 + p;
      float v[8];
#pragma unroll
      for (int e = 0; e < 8; ++e) v[e] = fbase[(size_t)(g * 8 + e) * kHW];
      uint4 pk;
      pk.x = pack2(v[0], v[1]);
      pk.y = pack2(v[2], v[3]);
      pk.z = pack2(v[4], v[5]);
      pk.w = pack2(v[6], v[7]);
      *reinterpret_cast<uint4*>(X + p * 64 + ((g ^ (p & 7)) * 8)) = pk;
    }
    lds_barrier();
#pragma unroll
    for (int ot = 0; ot < 2; ++ot)
#pragma unroll
      for (int ks = 0; ks < 2; ++ks)
        wf2[ot][ks] = *reinterpret_cast<const bf16x8*>(
            wb + OFF_W2 + ((wave * 2 + ot) * 16 + l15) * 64 + ks * 32 + quad * 8);
    load_bv2(bv2, bws + 192);
#pragma unroll
    for (int i = 0; i < 2; ++i) {
      bf16x8 a[2];
      read_af2(a, X, p0 + i);
      f32x4 acc = bv0;
      acc = mf(wf0[0], a[0], acc); acc = mf(wf0[1], a[1], acc);
      epilogue_sin<64>(acc, Y, (p0 + i) * 16 + l15, wlo * 2 + (quad >> 1), quad, sw);
    }
  }
  lds_barrier();

  // ---------- L1: Y -> X (wave handles pts p0, p0+1) ----------
  {
    bf16x8 a0[2], a1[2];
    read_af2(a0, Y, p0);
    read_af2(a1, Y, p0 + 1);
    f32x4 acc;
    acc = bv1; acc = mf(wf1[0], a0[0], acc); acc = mf(wf1[1], a0[1], acc);
    epilogue_sin<64>(acc, X, p0 * 16 + l15, wlo * 2 + (quad >> 1), quad, sw);
    acc = bv1; acc = mf(wf1[0], a1[0], acc); acc = mf(wf1[1], a1[1], acc);
    epilogue_sin<64>(acc, X, (p0 + 1) * 16 + l15, wlo * 2 + (quad >> 1), quad, sw);
  }
  lds_barrier();

  // ---------- L2: X -> A32 (each wave: all 4 pts, 2 out tiles) ; tail-prefetch wf3 ----------
  bf16x8 wf3[2][8];
  f32x4  bv3[2];
  {
    bf16x8 a0[2], a1[2];
    read_af2(a0, X, 0);
    read_af2(a1, X, 1);
    {
      f32x4 acc[2];
#pragma unroll
      for (int ot = 0; ot < 2; ++ot) {
        acc[ot] = bv2[ot];
        acc[ot] = mf(wf2[ot][0], a0[0], acc[ot]);
        acc[ot] = mf(wf2[ot][1], a0[1], acc[ot]);
      }
      read_af2(a0, X, 2);
      epi_pt2(acc, A32, 0);
    }
    {
      f32x4 acc[2];
#pragma unroll
      for (int ot = 0; ot < 2; ++ot) {
        acc[ot] = bv2[ot];
        acc[ot] = mf(wf2[ot][0], a1[0], acc[ot]);
        acc[ot] = mf(wf2[ot][1], a1[1], acc[ot]);
      }
      read_af2(a1, X, 3);
      epi_pt2(acc, A32, 1);
    }
    {
      f32x4 acc[2];
#pragma unroll
      for (int ot = 0; ot < 2; ++ot) {
        acc[ot] = bv2[ot];
        acc[ot] = mf(wf2[ot][0], a0[0], acc[ot]);
        acc[ot] = mf(wf2[ot][1], a0[1], acc[ot]);
      }
      epi_pt2(acc, A32, 2);
    }
    {
      f32x4 acc[2];
#pragma unroll
      for (int ot = 0; ot < 2; ++ot) {
        acc[ot] = bv2[ot];
        acc[ot] = mf(wf2[ot][0], a1[0], acc[ot]);
        acc[ot] = mf(wf2[ot][1], a1[1], acc[ot]);
      }
      // wf2 dead; wf3 loads fly over epi+barrier (64 regs, nothing else big live)
      __builtin_amdgcn_sched_barrier(0);
      load_wf8(wf3, wb + OFF_W3);
      load_bv2(bv3, bws + 448);
      epi_pt2(acc, A32, 3);
    }
  }
  lds_barrier();

  // ---------- L3: A32 -> B32 ; HALF-prefetch wf4 at tail (32 regs in flight) ----------
  bf16x8 wf4[2][8];
  f32x4  bv4[2];
  {
    bf16x8 af[8];
    f32x4 acc[2];
    read_af8(af, A32, 0);
    mfma_pt2(acc, wf3, af, bv3);
    read_af8(af, A32, 1);
    epi_pt2(acc, B32, 0);
    mfma_pt2(acc, wf3, af, bv3);
    read_af8(af, A32, 2);
    epi_pt2(acc, B32, 1);
    mfma_pt2(acc, wf3, af, bv3);
    read_af8(af, A32, 3);
    epi_pt2(acc, B32, 2);
    mfma_pt2(acc, wf3, af, bv3);
    // Pin: do NOT let these loads hoist into wf3's live range (R1 spill cause).
    __builtin_amdgcn_sched_barrier(0);
    load_wf8_ot(wf4, wb + OFF_W4, 0);   // first half only: 32 regs in flight
    load_bv2(bv4, bws + 704);
    epi_pt2(acc, B32, 3);
  }
  lds_barrier();

  // ---------- L4: B32 -> A32 ; head-load wf4 second half; tail-prefetch wf5 ----------
  bf16x8 wf5[8];
  f32x4  bv5;
  {
    load_wf8_ot(wf4, wb + OFF_W4, 1);   // second half at head (wf3 regs now free)
    bf16x8 af[8];
    f32x4 acc[2];
    read_af8(af, B32, 0);
    mfma_pt2(acc, wf4, af, bv4);
    read_af8(af, B32, 1);
    epi_pt2(acc, A32, 0);
    mfma_pt2(acc, wf4, af, bv4);
    read_af8(af, B32, 2);
    epi_pt2(acc, A32, 1);
    mfma_pt2(acc, wf4, af, bv4);
    read_af8(af, B32, 3);
    epi_pt2(acc, A32, 2);
    mfma_pt2(acc, wf4, af, bv4);
    __builtin_amdgcn_sched_barrier(0);
#pragma unroll
    for (int ks = 0; ks < 8; ++ks)  // wf5: 32 regs (col tile = wlo); wf4 dead
      wf5[ks] = *reinterpret_cast<const bf16x8*>(
          wb + OFF_W5 + (wlo * 16 + l15) * 256 + ks * 32 + quad * 8);
    bv5 = *reinterpret_cast<const f32x4*>(bws + 960 + wlo * 16 + quad * 4);
    epi_pt2(acc, A32, 3);
  }
  lds_barrier();

  // ---------- L5: A32 -> global (wave: pts p0,p0+1; col tile wlo) ----------
  {
    float* out_base = out + (size_t)(c * 2 + bq) * 64 * kHW + hw0;
    bf16x8 af[8];
#pragma unroll
    for (int i = 0; i < 2; ++i) {
      const int pt = p0 + i;
      read_af8(af, A32, pt);
      f32x4 acc = bv5;
#pragma unroll
      for (int ks = 0; ks < 8; ++ks) acc = mf(wf5[ks], af[ks], acc);
      const int p = pt * 16 + l15;
      const int o = wlo * 16 + quad * 4;
      float* dst = out_base + (size_t)o * kHW + p;
#pragma unroll
      for (int r = 0; r < 4; ++r) dst[(size_t)r * kHW] = acc[r];
    }
  }
}

extern "C" void kernel_launch(void* const* d_in, const int* in_sizes, int n_in,
                              void* d_out, int out_size, void* d_ws, size_t ws_size,
                              hipStream_t stream) {
  const float* feat  = (const float*)d_in[0];
  const float* times = (const float*)d_in[1];
  const float* w0 = (const float*)d_in[2];
  const float* b0 = (const float*)d_in[3];
  const float* w1 = (const float*)d_in[4];
  const float* b1 = (const float*)d_in[5];
  const float* w2 = (const float*)d_in[6];
  const float* b2 = (const float*)d_in[7];
  const float* w3 = (const float*)d_in[8];
  const float* b3 = (const float*)d_in[9];
  const float* w4 = (const float*)d_in[10];
  const float* b4 = (const float*)d_in[11];
  const float* w5 = (const float*)d_in[12];
  const float* b5 = (const float*)d_in[13];
  u16*   wb  = (u16*)d_ws;
  float* bws = (float*)((char*)d_ws + (size_t)W_TOTAL * 2);
  float* out = (float*)d_out;

  convert_weights<<<(W_TOTAL + B_TOTAL) / 256, 256, 0, stream>>>(
      w0, w1, w2, w3, w4, w5, b0, b1, b2, b3, b4, b5, wb, bws);

  if (ws_size >= WS_NEED) {
    u16* featT = (u16*)((char*)d_ws + FEAT_BYTE_OFF);
    convert_feat<<<1920, 256, 0, stream>>>(feat, featT);
    siren_main<true><<<5760, 512, 0, stream>>>(feat, times, wb, bws, featT, out);
  } else {
    siren_main<false><<<5760, 512, 0, stream>>>(feat, times, wb, bws, wb, out);
  }
}

// Round 5
// 393.513 us; speedup vs baseline: 1.0846x; 1.0547x over previous
//
#include <hip/hip_runtime.h>
#include <hip/hip_bf16.h>

typedef __bf16 bf16_t;
typedef bf16_t bf16x8 __attribute__((ext_vector_type(8)));
typedef float f32x4 __attribute__((ext_vector_type(4)));
typedef unsigned short u16;
typedef unsigned int u32;

static constexpr int kHW = 192 * 320;          // 61440
static constexpr float kC = 4.77464829275686f; // 30 / (2*pi)

__device__ __forceinline__ u16 f2bf(float f) {
  u32 u = __float_as_uint(f);
  return (u16)((u + 0x7FFFu + ((u >> 16) & 1u)) >> 16);
}

__device__ __forceinline__ u32 pack2(float a, float b) {
  __hip_bfloat162 h = __float22bfloat162_rn(make_float2(a, b));
  union { __hip_bfloat162 h2; u32 u; } cv;
  cv.h2 = h;
  return cv.u;
}

// LDS-visibility-only barrier: leaves global loads (weight prefetch) in flight.
__device__ __forceinline__ void lds_barrier() {
  __asm__ volatile("s_waitcnt lgkmcnt(0)\n\ts_barrier" ::: "memory");
}

// ---- d_ws layout ----
static constexpr int OFF_W0 = 0;        // [64][64] (t-col folded to bias)
static constexpr int OFF_W1 = 4096;     // [64][64]
static constexpr int OFF_W2 = 8192;     // [256][64]
static constexpr int OFF_W3 = 24576;    // [256][256]
static constexpr int OFF_W4 = 90112;    // [256][256]
static constexpr int OFF_W5 = 155648;   // [64][256] (not scaled)
static constexpr int W_TOTAL = 172032;
static constexpr int B_TOTAL = 1024;
static constexpr size_t FEAT_BYTE_OFF = 348160;
static constexpr size_t WS_NEED = FEAT_BYTE_OFF + (size_t)1920 * 8192;

__global__ void convert_weights(const float* __restrict__ w0, const float* __restrict__ w1,
                                const float* __restrict__ w2, const float* __restrict__ w3,
                                const float* __restrict__ w4, const float* __restrict__ w5,
                                const float* __restrict__ b0, const float* __restrict__ b1,
                                const float* __restrict__ b2, const float* __restrict__ b3,
                                const float* __restrict__ b4, const float* __restrict__ b5,
                                u16* __restrict__ wb, float* __restrict__ bws) {
  int i = blockIdx.x * 256 + threadIdx.x;
  if (i < W_TOTAL) {
    float v, s = kC;
    if (i < OFF_W1)      { int o = i >> 6, k = i & 63; v = w0[o * 65 + k]; }
    else if (i < OFF_W2) { v = w1[i - OFF_W1]; }
    else if (i < OFF_W3) { v = w2[i - OFF_W2]; }
    else if (i < OFF_W4) { v = w3[i - OFF_W3]; }
    else if (i < OFF_W5) { v = w4[i - OFF_W4]; }
    else                 { v = w5[i - OFF_W5]; s = 1.0f; }
    wb[i] = f2bf(v * s);
  } else {
    int j = i - W_TOTAL;
    float v;
    if (j < 64)       v = kC * b0[j];
    else if (j < 128) v = kC * w0[(j - 64) * 65 + 64];
    else if (j < 192) v = kC * b1[j - 128];
    else if (j < 448) v = kC * b2[j - 192];
    else if (j < 704) v = kC * b3[j - 448];
    else if (j < 960) v = kC * b4[j - 704];
    else              v = b5[j - 960];
    bws[j] = v;
  }
}

// Pre-transpose feat into the swizzled bf16 image (the exact L0 A-frag layout).
__global__ void convert_feat(const float* __restrict__ feat, u16* __restrict__ featT) {
  const int chunk = blockIdx.x;
  const int bq  = chunk / 960;
  const int hw0 = (chunk % 960) * 64;
  const int tid = threadIdx.x;
  const int p   = tid & 63;
  const int gg  = tid >> 6;
  const float* fbase = feat + (size_t)bq * 64 * kHW + hw0 + p;
  u16* img = featT + (size_t)chunk * 4096;
#pragma unroll
  for (int j = 0; j < 2; ++j) {
    const int g = gg * 2 + j;
    float v[8];
#pragma unroll
    for (int e = 0; e < 8; ++e) v[e] = fbase[(size_t)(g * 8 + e) * kHW];
    uint4 pk;
    pk.x = pack2(v[0], v[1]);
    pk.y = pack2(v[2], v[3]);
    pk.z = pack2(v[4], v[5]);
    pk.w = pack2(v[6], v[7]);
    *reinterpret_cast<uint4*>(img + p * 64 + ((g ^ (p & 7)) * 8)) = pk;
  }
}

template<int RSO>
__device__ __forceinline__ void epilogue_sin(f32x4 acc, u16* outb, int p, int g,
                                             int quad, int sw) {
  float s0 = __builtin_amdgcn_sinf(__builtin_amdgcn_fractf(acc[0]));
  float s1 = __builtin_amdgcn_sinf(__builtin_amdgcn_fractf(acc[1]));
  float s2 = __builtin_amdgcn_sinf(__builtin_amdgcn_fractf(acc[2]));
  float s3 = __builtin_amdgcn_sinf(__builtin_amdgcn_fractf(acc[3]));
  uint2 v;
  v.x = pack2(s0, s1);
  v.y = pack2(s2, s3);
  *reinterpret_cast<uint2*>(outb + p * RSO + ((g ^ sw) * 8) + (quad & 1) * 4) = v;
}

__device__ __forceinline__ f32x4 mf(bf16x8 a, bf16x8 b, f32x4 c) {
  return __builtin_amdgcn_mfma_f32_16x16x32_bf16(a, b, c, 0, 0, 0);
}

template<bool PRE>
__global__ __attribute__((amdgpu_waves_per_eu(2, 2)))
void __launch_bounds__(256)
siren_main(const float* __restrict__ feat, const float* __restrict__ times,
           const u16* __restrict__ wb, const float* __restrict__ bws,
           const u16* __restrict__ featT, float* __restrict__ out) {
  __shared__ __align__(16) u16 A32[64 * 256];   // 32 KB
  __shared__ __align__(16) u16 B32[64 * 256];   // 32 KB
  u16* X = B32;         // 64x64 compact (stride 64), aliases B32 (dead by L3)
  u16* Y = B32 + 4096;

  const int tid   = threadIdx.x;
  const int bid   = blockIdx.x;
  const int c     = bid / 1920;
  const int chunk = bid % 1920;
  const int bq    = chunk / 960;
  const int hw0   = (chunk % 960) * 64;
  const float t   = times[c];
  const int wave  = tid >> 6;
  const int lane  = tid & 63;
  const int l15   = lane & 15;
  const int quad  = lane >> 4;
  const int sw    = l15 & 7;

  // Anti-convoy skew: round-1 blocks launch 2-per-CU simultaneously
  // (partners bid and bid+256 under 8-XCD round-robin). Sleep ~8k cycles
  // (~1.5 layer-phases of the ~31k-cycle block pipeline) on one partner so
  // the pair runs anti-phased: one block's LDS burst overlaps the other's
  // weight-stream/MFMA phase. Later rounds inherit the stagger via
  // end-time offsets. Sleep is free on the CU (partner runs during it).
  if (bid < 512 && ((bid >> 8) & 1)) __builtin_amdgcn_s_sleep(127);

  // ---------- helpers ----------
  auto read_af8 = [&](bf16x8 (&af)[8], const u16* in, int pt) {
#pragma unroll
    for (int ks = 0; ks < 8; ++ks)
      af[ks] = *reinterpret_cast<const bf16x8*>(
          in + (pt * 16 + l15) * 256 + (((ks * 4 + quad) ^ sw) * 8));
  };
  auto read_af2 = [&](bf16x8 (&af)[2], const u16* in, int pt) {
#pragma unroll
    for (int ks = 0; ks < 2; ++ks)
      af[ks] = *reinterpret_cast<const bf16x8*>(
          in + (pt * 16 + l15) * 64 + (((ks * 4 + quad) ^ sw) * 8));
  };
  auto load_wf_half = [&](bf16x8 (&wf)[4][4], const u16* wbase, int kh) {
#pragma unroll
    for (int ks = 0; ks < 4; ++ks)
#pragma unroll
      for (int ot = 0; ot < 4; ++ot)
        wf[ot][ks] = *reinterpret_cast<const bf16x8*>(
            wbase + ((wave * 4 + ot) * 16 + l15) * 256 + (kh * 4 + ks) * 32 + quad * 8);
  };
  auto load_bv4 = [&](f32x4 (&bv)[4], const float* bg) {
#pragma unroll
    for (int ot = 0; ot < 4; ++ot)
      bv[ot] = *reinterpret_cast<const f32x4*>(bg + (wave * 4 + ot) * 16 + quad * 4);
  };
  auto mfma_pt = [&](f32x4 (&acc)[4], bf16x8 (&wa)[4][4], bf16x8 (&wbh)[4][4],
                     bf16x8 (&af)[8], const f32x4 (&bv)[4]) {
#pragma unroll
    for (int ot = 0; ot < 4; ++ot) acc[ot] = bv[ot];
#pragma unroll
    for (int ks = 0; ks < 8; ++ks)
#pragma unroll
      for (int ot = 0; ot < 4; ++ot)
        acc[ot] = mf(ks < 4 ? wa[ot][ks] : wbh[ot][ks - 4], af[ks], acc[ot]);
  };
  auto epi_pt4 = [&](f32x4 (&acc)[4], u16* outb, int pt) {
#pragma unroll
    for (int ot = 0; ot < 4; ++ot)
      epilogue_sin<256>(acc[ot], outb, pt * 16 + l15,
                        (wave * 4 + ot) * 2 + (quad >> 1), quad, sw);
  };

  // ---------- preload L0/L1 weights + biases ----------
  bf16x8 wf0[2], wf1[2];
#pragma unroll
  for (int ks = 0; ks < 2; ++ks) {
    wf0[ks] = *reinterpret_cast<const bf16x8*>(wb + OFF_W0 + (wave * 16 + l15) * 64 + ks * 32 + quad * 8);
    wf1[ks] = *reinterpret_cast<const bf16x8*>(wb + OFF_W1 + (wave * 16 + l15) * 64 + ks * 32 + quad * 8);
  }
  f32x4 bv0, bv1;
  {
    f32x4 cb = *reinterpret_cast<const f32x4*>(bws + wave * 16 + quad * 4);
    f32x4 cw = *reinterpret_cast<const f32x4*>(bws + 64 + wave * 16 + quad * 4);
#pragma unroll
    for (int r = 0; r < 4; ++r) bv0[r] = cb[r] + t * cw[r];
    bv1 = *reinterpret_cast<const f32x4*>(bws + 128 + wave * 16 + quad * 4);
  }

  bf16x8 wf2[4][2];
  f32x4  bv2[4];

  // ---------- L0: featT(global) or X(LDS) -> Y ----------
  if constexpr (PRE) {
    const u16* fsrc = featT + (size_t)chunk * 4096;
    bf16x8 a0[2], a1[2];
    auto rdg = [&](bf16x8 (&a)[2], int pt) {
#pragma unroll
      for (int ks = 0; ks < 2; ++ks)
        a[ks] = *reinterpret_cast<const bf16x8*>(
            fsrc + (pt * 16 + l15) * 64 + (((ks * 4 + quad) ^ sw) * 8));
    };
    rdg(a0, 0);
    rdg(a1, 1);
    // L2-layer weights: issue now, consumed two layers later
#pragma unroll
    for (int ks = 0; ks < 2; ++ks)
#pragma unroll
      for (int ot = 0; ot < 4; ++ot)
        wf2[ot][ks] = *reinterpret_cast<const bf16x8*>(
            wb + OFF_W2 + ((wave * 4 + ot) * 16 + l15) * 64 + ks * 32 + quad * 8);
    load_bv4(bv2, bws + 192);

    f32x4 acc;
    acc = bv0; acc = mf(wf0[0], a0[0], acc); acc = mf(wf0[1], a0[1], acc);
    rdg(a0, 2);
    epilogue_sin<64>(acc, Y, 0 * 16 + l15, wave * 2 + (quad >> 1), quad, sw);
    acc = bv0; acc = mf(wf0[0], a1[0], acc); acc = mf(wf0[1], a1[1], acc);
    rdg(a1, 3);
    epilogue_sin<64>(acc, Y, 1 * 16 + l15, wave * 2 + (quad >> 1), quad, sw);
    acc = bv0; acc = mf(wf0[0], a0[0], acc); acc = mf(wf0[1], a0[1], acc);
    epilogue_sin<64>(acc, Y, 2 * 16 + l15, wave * 2 + (quad >> 1), quad, sw);
    acc = bv0; acc = mf(wf0[0], a1[0], acc); acc = mf(wf0[1], a1[1], acc);
    epilogue_sin<64>(acc, Y, 3 * 16 + l15, wave * 2 + (quad >> 1), quad, sw);
  } else {
    // fallback: stage into X, then classic LDS path
    {
      const int p  = tid & 63;
      const int gg = tid >> 6;
      const float* fbase = feat + (size_t)bq * 64 * kHW + hw0 + p;
#pragma unroll
      for (int j = 0; j < 2; ++j) {
        const int g = gg * 2 + j;
        float v[8];
#pragma unroll
        for (int e = 0; e < 8; ++e) v[e] = fbase[(size_t)(g * 8 + e) * kHW];
        uint4 pk;
        pk.x = pack2(v[0], v[1]);
        pk.y = pack2(v[2], v[3]);
        pk.z = pack2(v[4], v[5]);
        pk.w = pack2(v[6], v[7]);
        *reinterpret_cast<uint4*>(X + p * 64 + ((g ^ (p & 7)) * 8)) = pk;
      }
    }
    lds_barrier();
#pragma unroll
    for (int ks = 0; ks < 2; ++ks)
#pragma unroll
      for (int ot = 0; ot < 4; ++ot)
        wf2[ot][ks] = *reinterpret_cast<const bf16x8*>(
            wb + OFF_W2 + ((wave * 4 + ot) * 16 + l15) * 64 + ks * 32 + quad * 8);
    load_bv4(bv2, bws + 192);
#pragma unroll
    for (int pt = 0; pt < 4; ++pt) {
      bf16x8 a[2];
      read_af2(a, X, pt);
      f32x4 acc = bv0;
      acc = mf(wf0[0], a[0], acc); acc = mf(wf0[1], a[1], acc);
      epilogue_sin<64>(acc, Y, pt * 16 + l15, wave * 2 + (quad >> 1), quad, sw);
    }
  }
  lds_barrier();

  // ---------- L1: Y -> X ; prefetch first half of L3 weights ----------
  bf16x8 wf3a[4][4], wf3b[4][4];
  f32x4  bv3[4];
  {
    bf16x8 a0[2], a1[2];
    read_af2(a0, Y, 0);
    read_af2(a1, Y, 1);
    load_wf_half(wf3a, wb + OFF_W3, 0);   // flies during L1+epi+barrier+L2
    load_bv4(bv3, bws + 448);
    f32x4 acc;
    acc = bv1; acc = mf(wf1[0], a0[0], acc); acc = mf(wf1[1], a0[1], acc);
    read_af2(a0, Y, 2);
    epilogue_sin<64>(acc, X, 0 * 16 + l15, wave * 2 + (quad >> 1), quad, sw);
    acc = bv1; acc = mf(wf1[0], a1[0], acc); acc = mf(wf1[1], a1[1], acc);
    read_af2(a1, Y, 3);
    epilogue_sin<64>(acc, X, 1 * 16 + l15, wave * 2 + (quad >> 1), quad, sw);
    acc = bv1; acc = mf(wf1[0], a0[0], acc); acc = mf(wf1[1], a0[1], acc);
    epilogue_sin<64>(acc, X, 2 * 16 + l15, wave * 2 + (quad >> 1), quad, sw);
    acc = bv1; acc = mf(wf1[0], a1[0], acc); acc = mf(wf1[1], a1[1], acc);
    epilogue_sin<64>(acc, X, 3 * 16 + l15, wave * 2 + (quad >> 1), quad, sw);
  }
  lds_barrier();

  // ---------- L2: X -> A32 (N=256, NOT=4) ; prefetch second half of L3 ----------
  {
    bf16x8 a0[2], a1[2];
    read_af2(a0, X, 0);
    read_af2(a1, X, 1);
    {
      f32x4 acc[4];
#pragma unroll
      for (int ot = 0; ot < 4; ++ot) {
        acc[ot] = bv2[ot];
        acc[ot] = mf(wf2[ot][0], a0[0], acc[ot]);
        acc[ot] = mf(wf2[ot][1], a0[1], acc[ot]);
      }
      read_af2(a0, X, 2);
      epi_pt4(acc, A32, 0);
    }
    {
      f32x4 acc[4];
#pragma unroll
      for (int ot = 0; ot < 4; ++ot) {
        acc[ot] = bv2[ot];
        acc[ot] = mf(wf2[ot][0], a1[0], acc[ot]);
        acc[ot] = mf(wf2[ot][1], a1[1], acc[ot]);
      }
      read_af2(a1, X, 3);
      epi_pt4(acc, A32, 1);
    }
    {
      f32x4 acc[4];
#pragma unroll
      for (int ot = 0; ot < 4; ++ot) {
        acc[ot] = bv2[ot];
        acc[ot] = mf(wf2[ot][0], a0[0], acc[ot]);
        acc[ot] = mf(wf2[ot][1], a0[1], acc[ot]);
      }
      load_wf_half(wf3b, wb + OFF_W3, 1);   // wf2 nearly dead; 64 regs free
      epi_pt4(acc, A32, 2);
    }
    {
      f32x4 acc[4];
#pragma unroll
      for (int ot = 0; ot < 4; ++ot) {
        acc[ot] = bv2[ot];
        acc[ot] = mf(wf2[ot][0], a1[0], acc[ot]);
        acc[ot] = mf(wf2[ot][1], a1[1], acc[ot]);
      }
      epi_pt4(acc, A32, 3);
    }
  }
  lds_barrier();

  // ---------- L3: A32 -> B32 ; af double-buffered; tail-prefetch wf4 first half ----------
  bf16x8 wf4a[4][4], wf4b[4][4];
  f32x4  bv4[4];
  {
    bf16x8 afA[8], afB[8];
    read_af8(afA, A32, 0);
    read_af8(afB, A32, 1);
    {
      f32x4 acc[4];
      mfma_pt(acc, wf3a, wf3b, afA, bv3);
      read_af8(afA, A32, 2);
      epi_pt4(acc, B32, 0);
    }
    {
      f32x4 acc[4];
      mfma_pt(acc, wf3a, wf3b, afB, bv3);
      read_af8(afB, A32, 3);
      epi_pt4(acc, B32, 1);
    }
    {
      f32x4 acc[4];
      mfma_pt(acc, wf3a, wf3b, afA, bv3);
      epi_pt4(acc, B32, 2);
    }
    {
      f32x4 acc[4];
      mfma_pt(acc, wf3a, wf3b, afB, bv3);
      load_wf_half(wf4a, wb + OFF_W4, 0);   // wf3 dead after this pt's MFMAs
      load_bv4(bv4, bws + 704);
      epi_pt4(acc, B32, 3);
    }
  }
  lds_barrier();

  // ---------- L4: B32 -> A32 ; head-load wf4 second half; tail-prefetch wf5 ----------
  bf16x8 wf5[8];
  f32x4  bv5;
  {
    load_wf_half(wf4b, wb + OFF_W4, 1);
    bf16x8 afA[8], afB[8];
    read_af8(afA, B32, 0);
    read_af8(afB, B32, 1);
    {
      f32x4 acc[4];
      mfma_pt(acc, wf4a, wf4b, afA, bv4);
      read_af8(afA, B32, 2);
      epi_pt4(acc, A32, 0);
    }
    {
      f32x4 acc[4];
      mfma_pt(acc, wf4a, wf4b, afB, bv4);
      read_af8(afB, B32, 3);
      epi_pt4(acc, A32, 1);
    }
    {
      f32x4 acc[4];
      mfma_pt(acc, wf4a, wf4b, afA, bv4);
      epi_pt4(acc, A32, 2);
    }
    {
      f32x4 acc[4];
      mfma_pt(acc, wf4a, wf4b, afB, bv4);
#pragma unroll
      for (int ks = 0; ks < 8; ++ks)        // wf5: 32 regs
        wf5[ks] = *reinterpret_cast<const bf16x8*>(
            wb + OFF_W5 + (wave * 16 + l15) * 256 + ks * 32 + quad * 8);
      bv5 = *reinterpret_cast<const f32x4*>(bws + 960 + wave * 16 + quad * 4);
      epi_pt4(acc, A32, 3);
    }
  }
  lds_barrier();

  // ---------- L5: A32 -> global ----------
  {
    float* out_base = out + (size_t)(c * 2 + bq) * 64 * kHW + hw0;
    bf16x8 afA[8], afB[8];
    read_af8(afA, A32, 0);
    read_af8(afB, A32, 1);
#pragma unroll
    for (int pt = 0; pt < 4; ++pt) {
      bf16x8 (&af)[8] = (pt & 1) ? afB : afA;
      f32x4 acc = bv5;
#pragma unroll
      for (int ks = 0; ks < 8; ++ks) acc = mf(wf5[ks], af[ks], acc);
      if (pt == 0) read_af8(afA, A32, 2);
      if (pt == 1) read_af8(afB, A32, 3);
      const int p = pt * 16 + l15;
      const int o = wave * 16 + quad * 4;
      float* dst = out_base + (size_t)o * kHW + p;
#pragma unroll
      for (int r = 0; r < 4; ++r) dst[(size_t)r * kHW] = acc[r];
    }
  }
}

extern "C" void kernel_launch(void* const* d_in, const int* in_sizes, int n_in,
                              void* d_out, int out_size, void* d_ws, size_t ws_size,
                              hipStream_t stream) {
  const float* feat  = (const float*)d_in[0];
  const float* times = (const float*)d_in[1];
  const float* w0 = (const float*)d_in[2];
  const float* b0 = (const float*)d_in[3];
  const float* w1 = (const float*)d_in[4];
  const float* b1 = (const float*)d_in[5];
  const float* w2 = (const float*)d_in[6];
  const float* b2 = (const float*)d_in[7];
  const float* w3 = (const float*)d_in[8];
  const float* b3 = (const float*)d_in[9];
  const float* w4 = (const float*)d_in[10];
  const float* b4 = (const float*)d_in[11];
  const float* w5 = (const float*)d_in[12];
  const float* b5 = (const float*)d_in[13];
  u16*   wb  = (u16*)d_ws;
  float* bws = (float*)((char*)d_ws + (size_t)W_TOTAL * 2);
  float* out = (float*)d_out;

  convert_weights<<<(W_TOTAL + B_TOTAL) / 256, 256, 0, stream>>>(
      w0, w1, w2, w3, w4, w5, b0, b1, b2, b3, b4, b5, wb, bws);

  if (ws_size >= WS_NEED) {
    u16* featT = (u16*)((char*)d_ws + FEAT_BYTE_OFF);
    convert_feat<<<1920, 256, 0, stream>>>(feat, featT);
    siren_main<true><<<5760, 256, 0, stream>>>(feat, times, wb, bws, featT, out);
  } else {
    siren_main<false><<<5760, 256, 0, stream>>>(feat, times, wb, bws, wb, out);
  }
}

// Round 6
// 386.524 us; speedup vs baseline: 1.1042x; 1.0181x over previous
//
#include <hip/hip_runtime.h>
#include <hip/hip_bf16.h>

typedef __bf16 bf16_t;
typedef bf16_t bf16x8 __attribute__((ext_vector_type(8)));
typedef float f32x4 __attribute__((ext_vector_type(4)));
typedef unsigned short u16;
typedef unsigned int u32;

static constexpr int kHW = 192 * 320;          // 61440
static constexpr float kC = 4.77464829275686f; // 30 / (2*pi)

__device__ __forceinline__ u16 f2bf(float f) {
  u32 u = __float_as_uint(f);
  return (u16)((u + 0x7FFFu + ((u >> 16) & 1u)) >> 16);
}

__device__ __forceinline__ u32 pack2(float a, float b) {
  __hip_bfloat162 h = __float22bfloat162_rn(make_float2(a, b));
  union { __hip_bfloat162 h2; u32 u; } cv;
  cv.h2 = h;
  return cv.u;
}

// LDS-visibility-only barrier: leaves global loads (weight prefetch) in flight.
__device__ __forceinline__ void lds_barrier() {
  __asm__ volatile("s_waitcnt lgkmcnt(0)\n\ts_barrier" ::: "memory");
}

// ---- d_ws layout ----
static constexpr int OFF_W0 = 0;        // [64][64] (t-col folded to bias)
static constexpr int OFF_W1 = 4096;     // [64][64]
static constexpr int OFF_W2 = 8192;     // [256][64]
static constexpr int OFF_W3 = 24576;    // [256][256]
static constexpr int OFF_W4 = 90112;    // [256][256]
static constexpr int OFF_W5 = 155648;   // [64][256] (not scaled)
static constexpr int W_TOTAL = 172032;
static constexpr int B_TOTAL = 1024;
static constexpr size_t FEAT_BYTE_OFF = 348160;
static constexpr size_t WS_NEED = FEAT_BYTE_OFF + (size_t)1920 * 8192;

__global__ void convert_weights(const float* __restrict__ w0, const float* __restrict__ w1,
                                const float* __restrict__ w2, const float* __restrict__ w3,
                                const float* __restrict__ w4, const float* __restrict__ w5,
                                const float* __restrict__ b0, const float* __restrict__ b1,
                                const float* __restrict__ b2, const float* __restrict__ b3,
                                const float* __restrict__ b4, const float* __restrict__ b5,
                                u16* __restrict__ wb, float* __restrict__ bws) {
  int i = blockIdx.x * 256 + threadIdx.x;
  if (i < W_TOTAL) {
    float v, s = kC;
    if (i < OFF_W1)      { int o = i >> 6, k = i & 63; v = w0[o * 65 + k]; }
    else if (i < OFF_W2) { v = w1[i - OFF_W1]; }
    else if (i < OFF_W3) { v = w2[i - OFF_W2]; }
    else if (i < OFF_W4) { v = w3[i - OFF_W3]; }
    else if (i < OFF_W5) { v = w4[i - OFF_W4]; }
    else                 { v = w5[i - OFF_W5]; s = 1.0f; }
    wb[i] = f2bf(v * s);
  } else {
    int j = i - W_TOTAL;
    float v;
    if (j < 64)       v = kC * b0[j];
    else if (j < 128) v = kC * w0[(j - 64) * 65 + 64];
    else if (j < 192) v = kC * b1[j - 128];
    else if (j < 448) v = kC * b2[j - 192];
    else if (j < 704) v = kC * b3[j - 448];
    else if (j < 960) v = kC * b4[j - 704];
    else              v = b5[j - 960];
    bws[j] = v;
  }
}

// Pre-transpose feat into the swizzled bf16 image (the exact L0 A-frag layout).
__global__ void convert_feat(const float* __restrict__ feat, u16* __restrict__ featT) {
  const int chunk = blockIdx.x;
  const int bq  = chunk / 960;
  const int hw0 = (chunk % 960) * 64;
  const int tid = threadIdx.x;
  const int p   = tid & 63;
  const int gg  = tid >> 6;
  const float* fbase = feat + (size_t)bq * 64 * kHW + hw0 + p;
  u16* img = featT + (size_t)chunk * 4096;
#pragma unroll
  for (int j = 0; j < 2; ++j) {
    const int g = gg * 2 + j;
    float v[8];
#pragma unroll
    for (int e = 0; e < 8; ++e) v[e] = fbase[(size_t)(g * 8 + e) * kHW];
    uint4 pk;
    pk.x = pack2(v[0], v[1]);
    pk.y = pack2(v[2], v[3]);
    pk.z = pack2(v[4], v[5]);
    pk.w = pack2(v[6], v[7]);
    *reinterpret_cast<uint4*>(img + p * 64 + ((g ^ (p & 7)) * 8)) = pk;
  }
}

template<int RSO>
__device__ __forceinline__ void epilogue_sin(f32x4 acc, u16* outb, int p, int g,
                                             int quad, int sw) {
  float s0 = __builtin_amdgcn_sinf(__builtin_amdgcn_fractf(acc[0]));
  float s1 = __builtin_amdgcn_sinf(__builtin_amdgcn_fractf(acc[1]));
  float s2 = __builtin_amdgcn_sinf(__builtin_amdgcn_fractf(acc[2]));
  float s3 = __builtin_amdgcn_sinf(__builtin_amdgcn_fractf(acc[3]));
  uint2 v;
  v.x = pack2(s0, s1);
  v.y = pack2(s2, s3);
  *reinterpret_cast<uint2*>(outb + p * RSO + ((g ^ sw) * 8) + (quad & 1) * 4) = v;
}

__device__ __forceinline__ f32x4 mf(bf16x8 a, bf16x8 b, f32x4 c) {
  return __builtin_amdgcn_mfma_f32_16x16x32_bf16(a, b, c, 0, 0, 0);
}

// R6: pt-pair interleaved inner loops. waves_per_eu(2,2) grants a 256-VGPR
// budget but the R0 code only used 128 (compiler's occupancy-step heuristic),
// which forbade overlapping one pt-tile's epilogue/reads with the next
// pt-tile's MFMA chain. Explicit two-pt interleave (2x acc, 2x af, woven
// MFMAs -> 8 independent chains in L3/L4) spends the free registers on ILP.
// Peak live ~252 regs; occupancy unchanged (2 blocks/CU, 2 waves/SIMD).
template<bool PRE>
__global__ __attribute__((amdgpu_waves_per_eu(2, 2)))
void __launch_bounds__(256)
siren_main(const float* __restrict__ feat, const float* __restrict__ times,
           const u16* __restrict__ wb, const float* __restrict__ bws,
           const u16* __restrict__ featT, float* __restrict__ out) {
  __shared__ __align__(16) u16 A32[64 * 256];   // 32 KB
  __shared__ __align__(16) u16 B32[64 * 256];   // 32 KB
  u16* X = B32;         // 64x64 compact (stride 64), aliases B32 (dead by L3)
  u16* Y = B32 + 4096;

  const int tid   = threadIdx.x;
  const int bid   = blockIdx.x;
  const int c     = bid / 1920;
  const int chunk = bid % 1920;
  const int bq    = chunk / 960;
  const int hw0   = (chunk % 960) * 64;
  const float t   = times[c];
  const int wave  = tid >> 6;
  const int lane  = tid & 63;
  const int l15   = lane & 15;
  const int quad  = lane >> 4;
  const int sw    = l15 & 7;

  // ---------- helpers ----------
  auto read_af8 = [&](bf16x8 (&af)[8], const u16* in, int pt) {
#pragma unroll
    for (int ks = 0; ks < 8; ++ks)
      af[ks] = *reinterpret_cast<const bf16x8*>(
          in + (pt * 16 + l15) * 256 + (((ks * 4 + quad) ^ sw) * 8));
  };
  auto read_af2 = [&](bf16x8 (&af)[2], const u16* in, int pt) {
#pragma unroll
    for (int ks = 0; ks < 2; ++ks)
      af[ks] = *reinterpret_cast<const bf16x8*>(
          in + (pt * 16 + l15) * 64 + (((ks * 4 + quad) ^ sw) * 8));
  };
  auto load_wf_half = [&](bf16x8 (&wf)[4][4], const u16* wbase, int kh) {
#pragma unroll
    for (int ks = 0; ks < 4; ++ks)
#pragma unroll
      for (int ot = 0; ot < 4; ++ot)
        wf[ot][ks] = *reinterpret_cast<const bf16x8*>(
            wbase + ((wave * 4 + ot) * 16 + l15) * 256 + (kh * 4 + ks) * 32 + quad * 8);
  };
  auto load_bv4 = [&](f32x4 (&bv)[4], const float* bg) {
#pragma unroll
    for (int ot = 0; ot < 4; ++ot)
      bv[ot] = *reinterpret_cast<const f32x4*>(bg + (wave * 4 + ot) * 16 + quad * 4);
  };
  // Two pt-tiles interleaved: 8 independent MFMA chains (4 ot x 2 pt).
  auto mfma_pair = [&](f32x4 (&accA)[4], f32x4 (&accB)[4],
                       bf16x8 (&wa)[4][4], bf16x8 (&wbh)[4][4],
                       bf16x8 (&afA)[8], bf16x8 (&afB)[8], const f32x4 (&bv)[4]) {
#pragma unroll
    for (int ot = 0; ot < 4; ++ot) { accA[ot] = bv[ot]; accB[ot] = bv[ot]; }
#pragma unroll
    for (int ks = 0; ks < 8; ++ks)
#pragma unroll
      for (int ot = 0; ot < 4; ++ot) {
        bf16x8 w = ks < 4 ? wa[ot][ks] : wbh[ot][ks - 4];
        accA[ot] = mf(w, afA[ks], accA[ot]);
        accB[ot] = mf(w, afB[ks], accB[ot]);
      }
  };
  auto epi_pt4 = [&](f32x4 (&acc)[4], u16* outb, int pt) {
#pragma unroll
    for (int ot = 0; ot < 4; ++ot)
      epilogue_sin<256>(acc[ot], outb, pt * 16 + l15,
                        (wave * 4 + ot) * 2 + (quad >> 1), quad, sw);
  };

  // ---------- preload L0/L1 weights + biases ----------
  bf16x8 wf0[2], wf1[2];
#pragma unroll
  for (int ks = 0; ks < 2; ++ks) {
    wf0[ks] = *reinterpret_cast<const bf16x8*>(wb + OFF_W0 + (wave * 16 + l15) * 64 + ks * 32 + quad * 8);
    wf1[ks] = *reinterpret_cast<const bf16x8*>(wb + OFF_W1 + (wave * 16 + l15) * 64 + ks * 32 + quad * 8);
  }
  f32x4 bv0, bv1;
  {
    f32x4 cb = *reinterpret_cast<const f32x4*>(bws + wave * 16 + quad * 4);
    f32x4 cw = *reinterpret_cast<const f32x4*>(bws + 64 + wave * 16 + quad * 4);
#pragma unroll
    for (int r = 0; r < 4; ++r) bv0[r] = cb[r] + t * cw[r];
    bv1 = *reinterpret_cast<const f32x4*>(bws + 128 + wave * 16 + quad * 4);
  }

  bf16x8 wf2[4][2];
  f32x4  bv2[4];

  // ---------- L0: featT(global) or X(LDS) -> Y ; 4-pt batched (4 chains) ----------
  if constexpr (PRE) {
    const u16* fsrc = featT + (size_t)chunk * 4096;
    bf16x8 a[4][2];
#pragma unroll
    for (int p = 0; p < 4; ++p)
#pragma unroll
      for (int ks = 0; ks < 2; ++ks)
        a[p][ks] = *reinterpret_cast<const bf16x8*>(
            fsrc + (p * 16 + l15) * 64 + (((ks * 4 + quad) ^ sw) * 8));
    // L2-layer weights: issue now, consumed two layers later
#pragma unroll
    for (int ks = 0; ks < 2; ++ks)
#pragma unroll
      for (int ot = 0; ot < 4; ++ot)
        wf2[ot][ks] = *reinterpret_cast<const bf16x8*>(
            wb + OFF_W2 + ((wave * 4 + ot) * 16 + l15) * 64 + ks * 32 + quad * 8);
    load_bv4(bv2, bws + 192);

    f32x4 accp[4];
#pragma unroll
    for (int p = 0; p < 4; ++p) accp[p] = bv0;
#pragma unroll
    for (int ks = 0; ks < 2; ++ks)
#pragma unroll
      for (int p = 0; p < 4; ++p) accp[p] = mf(wf0[ks], a[p][ks], accp[p]);
#pragma unroll
    for (int p = 0; p < 4; ++p)
      epilogue_sin<64>(accp[p], Y, p * 16 + l15, wave * 2 + (quad >> 1), quad, sw);
  } else {
    // fallback: stage into X, then classic LDS path
    {
      const int p  = tid & 63;
      const int gg = tid >> 6;
      const float* fbase = feat + (size_t)bq * 64 * kHW + hw0 + p;
#pragma unroll
      for (int j = 0; j < 2; ++j) {
        const int g = gg * 2 + j;
        float v[8];
#pragma unroll
        for (int e = 0; e < 8; ++e) v[e] = fbase[(size_t)(g * 8 + e) * kHW];
        uint4 pk;
        pk.x = pack2(v[0], v[1]);
        pk.y = pack2(v[2], v[3]);
        pk.z = pack2(v[4], v[5]);
        pk.w = pack2(v[6], v[7]);
        *reinterpret_cast<uint4*>(X + p * 64 + ((g ^ (p & 7)) * 8)) = pk;
      }
    }
    lds_barrier();
#pragma unroll
    for (int ks = 0; ks < 2; ++ks)
#pragma unroll
      for (int ot = 0; ot < 4; ++ot)
        wf2[ot][ks] = *reinterpret_cast<const bf16x8*>(
            wb + OFF_W2 + ((wave * 4 + ot) * 16 + l15) * 64 + ks * 32 + quad * 8);
    load_bv4(bv2, bws + 192);
#pragma unroll
    for (int pt = 0; pt < 4; ++pt) {
      bf16x8 a[2];
      read_af2(a, X, pt);
      f32x4 acc = bv0;
      acc = mf(wf0[0], a[0], acc); acc = mf(wf0[1], a[1], acc);
      epilogue_sin<64>(acc, Y, pt * 16 + l15, wave * 2 + (quad >> 1), quad, sw);
    }
  }
  lds_barrier();

  // ---------- L1: Y -> X ; 4-pt batched ; prefetch first half of L3 ----------
  bf16x8 wf3a[4][4], wf3b[4][4];
  f32x4  bv3[4];
  {
    bf16x8 a[4][2];
    read_af2(a[0], Y, 0);
    read_af2(a[1], Y, 1);
    read_af2(a[2], Y, 2);
    read_af2(a[3], Y, 3);
    load_wf_half(wf3a, wb + OFF_W3, 0);   // flies during L1+epi+barrier+L2
    load_bv4(bv3, bws + 448);
    f32x4 accp[4];
#pragma unroll
    for (int p = 0; p < 4; ++p) accp[p] = bv1;
#pragma unroll
    for (int ks = 0; ks < 2; ++ks)
#pragma unroll
      for (int p = 0; p < 4; ++p) accp[p] = mf(wf1[ks], a[p][ks], accp[p]);
#pragma unroll
    for (int p = 0; p < 4; ++p)
      epilogue_sin<64>(accp[p], X, p * 16 + l15, wave * 2 + (quad >> 1), quad, sw);
  }
  lds_barrier();

  // ---------- L2: X -> A32 (N=256) ; pt-pair interleaved ; prefetch L3 half 2 ----------
  {
    bf16x8 aA[2], aB[2];
    read_af2(aA, X, 0);
    read_af2(aB, X, 1);
    f32x4 accA[4], accB[4];
    // pair (0,1)
#pragma unroll
    for (int ot = 0; ot < 4; ++ot) { accA[ot] = bv2[ot]; accB[ot] = bv2[ot]; }
#pragma unroll
    for (int ks = 0; ks < 2; ++ks)
#pragma unroll
      for (int ot = 0; ot < 4; ++ot) {
        accA[ot] = mf(wf2[ot][ks], aA[ks], accA[ot]);
        accB[ot] = mf(wf2[ot][ks], aB[ks], accB[ot]);
      }
    read_af2(aA, X, 2);
    read_af2(aB, X, 3);
    epi_pt4(accA, A32, 0);
    epi_pt4(accB, A32, 1);
    // pair (2,3)
#pragma unroll
    for (int ot = 0; ot < 4; ++ot) { accA[ot] = bv2[ot]; accB[ot] = bv2[ot]; }
#pragma unroll
    for (int ks = 0; ks < 2; ++ks)
#pragma unroll
      for (int ot = 0; ot < 4; ++ot) {
        accA[ot] = mf(wf2[ot][ks], aA[ks], accA[ot]);
        accB[ot] = mf(wf2[ot][ks], aB[ks], accB[ot]);
      }
    load_wf_half(wf3b, wb + OFF_W3, 1);   // wf2 nearly dead; regs free
    epi_pt4(accA, A32, 2);
    epi_pt4(accB, A32, 3);
  }
  lds_barrier();

  // ---------- L3: A32 -> B32 ; pt-pair interleaved (8 chains) ; tail-prefetch wf4a ----------
  bf16x8 wf4a[4][4], wf4b[4][4];
  f32x4  bv4[4];
  {
    bf16x8 afA[8], afB[8];
    read_af8(afA, A32, 0);
    read_af8(afB, A32, 1);
    f32x4 accA[4], accB[4];
    // pair (0,1)
    mfma_pair(accA, accB, wf3a, wf3b, afA, afB, bv3);
    read_af8(afA, A32, 2);
    read_af8(afB, A32, 3);
    epi_pt4(accA, B32, 0);
    epi_pt4(accB, B32, 1);
    // pair (2,3)
    mfma_pair(accA, accB, wf3a, wf3b, afA, afB, bv3);
    load_wf_half(wf4a, wb + OFF_W4, 0);   // wf3 dead after this pair's MFMAs
    load_bv4(bv4, bws + 704);
    epi_pt4(accA, B32, 2);
    epi_pt4(accB, B32, 3);
  }
  lds_barrier();

  // ---------- L4: B32 -> A32 ; head-load wf4b ; pt-pair interleaved ; tail wf5 ----------
  bf16x8 wf5[8];
  f32x4  bv5;
  {
    load_wf_half(wf4b, wb + OFF_W4, 1);
    bf16x8 afA[8], afB[8];
    read_af8(afA, B32, 0);
    read_af8(afB, B32, 1);
    f32x4 accA[4], accB[4];
    // pair (0,1)
    mfma_pair(accA, accB, wf4a, wf4b, afA, afB, bv4);
    read_af8(afA, B32, 2);
    read_af8(afB, B32, 3);
    epi_pt4(accA, A32, 0);
    epi_pt4(accB, A32, 1);
    // pair (2,3)
    mfma_pair(accA, accB, wf4a, wf4b, afA, afB, bv4);
#pragma unroll
    for (int ks = 0; ks < 8; ++ks)        // wf5: 32 regs; wf4 dead
      wf5[ks] = *reinterpret_cast<const bf16x8*>(
          wb + OFF_W5 + (wave * 16 + l15) * 256 + ks * 32 + quad * 8);
    bv5 = *reinterpret_cast<const f32x4*>(bws + 960 + wave * 16 + quad * 4);
    epi_pt4(accA, A32, 2);
    epi_pt4(accB, A32, 3);
  }
  lds_barrier();

  // ---------- L5: A32 -> global ; pt-pair interleaved (2 chains) ----------
  {
    float* out_base = out + (size_t)(c * 2 + bq) * 64 * kHW + hw0;
    const int o = wave * 16 + quad * 4;
    bf16x8 afA[8], afB[8];
    read_af8(afA, A32, 0);
    read_af8(afB, A32, 1);
#pragma unroll
    for (int pp = 0; pp < 2; ++pp) {
      f32x4 accA = bv5, accB = bv5;
#pragma unroll
      for (int ks = 0; ks < 8; ++ks) {
        accA = mf(wf5[ks], afA[ks], accA);
        accB = mf(wf5[ks], afB[ks], accB);
      }
      if (pp == 0) { read_af8(afA, A32, 2); read_af8(afB, A32, 3); }
      const int ptA = pp * 2, ptB = pp * 2 + 1;
      float* dstA = out_base + (size_t)o * kHW + (ptA * 16 + l15);
      float* dstB = out_base + (size_t)o * kHW + (ptB * 16 + l15);
#pragma unroll
      for (int r = 0; r < 4; ++r) dstA[(size_t)r * kHW] = accA[r];
#pragma unroll
      for (int r = 0; r < 4; ++r) dstB[(size_t)r * kHW] = accB[r];
    }
  }
}

extern "C" void kernel_launch(void* const* d_in, const int* in_sizes, int n_in,
                              void* d_out, int out_size, void* d_ws, size_t ws_size,
                              hipStream_t stream) {
  const float* feat  = (const float*)d_in[0];
  const float* times = (const float*)d_in[1];
  const float* w0 = (const float*)d_in[2];
  const float* b0 = (const float*)d_in[3];
  const float* w1 = (const float*)d_in[4];
  const float* b1 = (const float*)d_in[5];
  const float* w2 = (const float*)d_in[6];
  const float* b2 = (const float*)d_in[7];
  const float* w3 = (const float*)d_in[8];
  const float* b3 = (const float*)d_in[9];
  const float* w4 = (const float*)d_in[10];
  const float* b4 = (const float*)d_in[11];
  const float* w5 = (const float*)d_in[12];
  const float* b5 = (const float*)d_in[13];
  u16*   wb  = (u16*)d_ws;
  float* bws = (float*)((char*)d_ws + (size_t)W_TOTAL * 2);
  float* out = (float*)d_out;

  convert_weights<<<(W_TOTAL + B_TOTAL) / 256, 256, 0, stream>>>(
      w0, w1, w2, w3, w4, w5, b0, b1, b2, b3, b4, b5, wb, bws);

  if (ws_size >= WS_NEED) {
    u16* featT = (u16*)((char*)d_ws + FEAT_BYTE_OFF);
    convert_feat<<<1920, 256, 0, stream>>>(feat, featT);
    siren_main<true><<<5760, 256, 0, stream>>>(feat, times, wb, bws, featT, out);
  } else {
    siren_main<false><<<5760, 256, 0, stream>>>(feat, times, wb, bws, wb, out);
  }
}

// Round 7
// 336.387 us; speedup vs baseline: 1.2688x; 1.1490x over previous
//
#include <hip/hip_runtime.h>
#include <hip/hip_bf16.h>

typedef __bf16 bf16_t;
typedef bf16_t bf16x8 __attribute__((ext_vector_type(8)));
typedef float f32x4 __attribute__((ext_vector_type(4)));
typedef unsigned short u16;
typedef unsigned int u32;

static constexpr int kHW = 192 * 320;          // 61440
static constexpr float kC = 4.77464829275686f; // 30 / (2*pi)

__device__ __forceinline__ u16 f2bf(float f) {
  u32 u = __float_as_uint(f);
  return (u16)((u + 0x7FFFu + ((u >> 16) & 1u)) >> 16);
}

__device__ __forceinline__ u32 pack2(float a, float b) {
  __hip_bfloat162 h = __float22bfloat162_rn(make_float2(a, b));
  union { __hip_bfloat162 h2; u32 u; } cv;
  cv.h2 = h;
  return cv.u;
}

// LDS-visibility-only barrier: leaves global loads (weight prefetch) in flight.
__device__ __forceinline__ void lds_barrier() {
  __asm__ volatile("s_waitcnt lgkmcnt(0)\n\ts_barrier" ::: "memory");
}

// ---- d_ws layout ----
static constexpr int OFF_W0 = 0;        // [64][64] (t-col folded to bias)
static constexpr int OFF_W1 = 4096;     // [64][64]
static constexpr int OFF_W2 = 8192;     // [256][64]
static constexpr int OFF_W3 = 24576;    // [256][256]
static constexpr int OFF_W4 = 90112;    // [256][256]
static constexpr int OFF_W5 = 155648;   // [64][256] (not scaled)
static constexpr int W_TOTAL = 172032;
static constexpr int B_TOTAL = 1024;
static constexpr size_t FEAT_BYTE_OFF = 348160;
static constexpr size_t WS_NEED = FEAT_BYTE_OFF + (size_t)1920 * 8192;

__global__ void convert_weights(const float* __restrict__ w0, const float* __restrict__ w1,
                                const float* __restrict__ w2, const float* __restrict__ w3,
                                const float* __restrict__ w4, const float* __restrict__ w5,
                                const float* __restrict__ b0, const float* __restrict__ b1,
                                const float* __restrict__ b2, const float* __restrict__ b3,
                                const float* __restrict__ b4, const float* __restrict__ b5,
                                u16* __restrict__ wb, float* __restrict__ bws) {
  int i = blockIdx.x * 256 + threadIdx.x;
  if (i < W_TOTAL) {
    float v, s = kC;
    if (i < OFF_W1)      { int o = i >> 6, k = i & 63; v = w0[o * 65 + k]; }
    else if (i < OFF_W2) { v = w1[i - OFF_W1]; }
    else if (i < OFF_W3) { v = w2[i - OFF_W2]; }
    else if (i < OFF_W4) { v = w3[i - OFF_W3]; }
    else if (i < OFF_W5) { v = w4[i - OFF_W4]; }
    else                 { v = w5[i - OFF_W5]; s = 1.0f; }
    wb[i] = f2bf(v * s);
  } else {
    int j = i - W_TOTAL;
    float v;
    if (j < 64)       v = kC * b0[j];
    else if (j < 128) v = kC * w0[(j - 64) * 65 + 64];
    else if (j < 192) v = kC * b1[j - 128];
    else if (j < 448) v = kC * b2[j - 192];
    else if (j < 704) v = kC * b3[j - 448];
    else if (j < 960) v = kC * b4[j - 704];
    else              v = b5[j - 960];
    bws[j] = v;
  }
}

// Pre-transpose feat into the swizzled bf16 image (the exact L0 A-frag layout).
__global__ void convert_feat(const float* __restrict__ feat, u16* __restrict__ featT) {
  const int chunk = blockIdx.x;
  const int bq  = chunk / 960;
  const int hw0 = (chunk % 960) * 64;
  const int tid = threadIdx.x;
  const int p   = tid & 63;
  const int gg  = tid >> 6;
  const float* fbase = feat + (size_t)bq * 64 * kHW + hw0 + p;
  u16* img = featT + (size_t)chunk * 4096;
#pragma unroll
  for (int j = 0; j < 2; ++j) {
    const int g = gg * 2 + j;
    float v[8];
#pragma unroll
    for (int e = 0; e < 8; ++e) v[e] = fbase[(size_t)(g * 8 + e) * kHW];
    uint4 pk;
    pk.x = pack2(v[0], v[1]);
    pk.y = pack2(v[2], v[3]);
    pk.z = pack2(v[4], v[5]);
    pk.w = pack2(v[6], v[7]);
    *reinterpret_cast<uint4*>(img + p * 64 + ((g ^ (p & 7)) * 8)) = pk;
  }
}

template<int RSO>
__device__ __forceinline__ void epilogue_sin(f32x4 acc, u16* outb, int p, int g,
                                             int quad, int sw) {
  float s0 = __builtin_amdgcn_sinf(__builtin_amdgcn_fractf(acc[0]));
  float s1 = __builtin_amdgcn_sinf(__builtin_amdgcn_fractf(acc[1]));
  float s2 = __builtin_amdgcn_sinf(__builtin_amdgcn_fractf(acc[2]));
  float s3 = __builtin_amdgcn_sinf(__builtin_amdgcn_fractf(acc[3]));
  uint2 v;
  v.x = pack2(s0, s1);
  v.y = pack2(s2, s3);
  *reinterpret_cast<uint2*>(outb + p * RSO + ((g ^ sw) * 8) + (quad & 1) * 4) = v;
}

__device__ __forceinline__ f32x4 mf(bf16x8 a, bf16x8 b, f32x4 c) {
  return __builtin_amdgcn_mfma_f32_16x16x32_bf16(a, b, c, 0, 0, 0);
}

// R7: 128-px blocks (512 threads, 8 waves, 128KB LDS, 1 block/CU, 2 waves/SIMD).
// Each wave owns 32 out-rows of the 256-wide layers -> weight frags 64 regs
// (was 128), so the NEXT layer's full weights prefetch mid-layer with a ~2k-cy
// window (was tail-issued, ~1k). Per-CU L2 weight traffic halves (336KB/128px);
// per-phase barrier/latency fixed costs amortize over 2x work. Same FLOPs,
// same layouts; featT chunks are contiguous so pt 0..7 indexing is seamless.
template<bool PRE>
__global__ __attribute__((amdgpu_waves_per_eu(2, 2)))
void __launch_bounds__(512)
siren_main(const float* __restrict__ feat, const float* __restrict__ times,
           const u16* __restrict__ wb, const float* __restrict__ bws,
           const u16* __restrict__ featT, float* __restrict__ out) {
  __shared__ __align__(16) u16 A32[128 * 256];   // 64 KB
  __shared__ __align__(16) u16 B32[128 * 256];   // 64 KB
  u16* X = B32;          // 128x64 compact (stride 64), aliases B32 (dead by L3)
  u16* Y = B32 + 8192;

  const int tid   = threadIdx.x;
  const int bid   = blockIdx.x;
  const int c     = bid / 960;
  const int pair  = bid % 960;     // covers old chunks 2*pair, 2*pair+1
  const int bq    = pair / 480;
  const int hw0   = (pair % 480) * 128;
  const float t   = times[c];
  const int wave  = tid >> 6;      // 0..7
  const int lane  = tid & 63;
  const int l15   = lane & 15;
  const int quad  = lane >> 4;
  const int sw    = l15 & 7;
  const int wlo   = wave & 3;      // col tile for 64-wide layers / L5
  const int p0    = (wave >> 2) * 4; // 64-wide layers / L5: pts p0..p0+3

  // ---------- helpers ----------
  auto read_af8 = [&](bf16x8 (&af)[8], const u16* in, int pt) {
#pragma unroll
    for (int ks = 0; ks < 8; ++ks)
      af[ks] = *reinterpret_cast<const bf16x8*>(
          in + (pt * 16 + l15) * 256 + (((ks * 4 + quad) ^ sw) * 8));
  };
  auto read_af2 = [&](bf16x8 (&af)[2], const u16* in, int pt) {
#pragma unroll
    for (int ks = 0; ks < 2; ++ks)
      af[ks] = *reinterpret_cast<const bf16x8*>(
          in + (pt * 16 + l15) * 64 + (((ks * 4 + quad) ^ sw) * 8));
  };
  // Full 256-wide weight fragment for this wave's 32 rows: 16 bf16x8 = 64 regs.
  auto load_wf16 = [&](bf16x8 (&wf)[2][8], const u16* wbase) {
#pragma unroll
    for (int ot = 0; ot < 2; ++ot)
#pragma unroll
      for (int ks = 0; ks < 8; ++ks)
        wf[ot][ks] = *reinterpret_cast<const bf16x8*>(
            wbase + ((wave * 2 + ot) * 16 + l15) * 256 + ks * 32 + quad * 8);
  };
  auto load_bv2 = [&](f32x4 (&bv)[2], const float* bg) {
#pragma unroll
    for (int ot = 0; ot < 2; ++ot)
      bv[ot] = *reinterpret_cast<const f32x4*>(bg + (wave * 2 + ot) * 16 + quad * 4);
  };
  // Two pt-tiles interleaved: 4 independent chains (2 ot x 2 pt).
  auto mfma_pair2 = [&](f32x4 (&accA)[2], f32x4 (&accB)[2], bf16x8 (&wf)[2][8],
                        bf16x8 (&afA)[8], bf16x8 (&afB)[8], const f32x4 (&bv)[2]) {
#pragma unroll
    for (int ot = 0; ot < 2; ++ot) { accA[ot] = bv[ot]; accB[ot] = bv[ot]; }
#pragma unroll
    for (int ks = 0; ks < 8; ++ks)
#pragma unroll
      for (int ot = 0; ot < 2; ++ot) {
        accA[ot] = mf(wf[ot][ks], afA[ks], accA[ot]);
        accB[ot] = mf(wf[ot][ks], afB[ks], accB[ot]);
      }
  };
  auto epi_pt2 = [&](f32x4 (&acc)[2], u16* outb, int pt) {
#pragma unroll
    for (int ot = 0; ot < 2; ++ot)
      epilogue_sin<256>(acc[ot], outb, pt * 16 + l15,
                        (wave * 2 + ot) * 2 + (quad >> 1), quad, sw);
  };

  // ---------- preload L0/L1 weights + biases (col tile = wlo) ----------
  bf16x8 wf0[2], wf1[2];
#pragma unroll
  for (int ks = 0; ks < 2; ++ks) {
    wf0[ks] = *reinterpret_cast<const bf16x8*>(wb + OFF_W0 + (wlo * 16 + l15) * 64 + ks * 32 + quad * 8);
    wf1[ks] = *reinterpret_cast<const bf16x8*>(wb + OFF_W1 + (wlo * 16 + l15) * 64 + ks * 32 + quad * 8);
  }
  f32x4 bv0, bv1;
  {
    f32x4 cb = *reinterpret_cast<const f32x4*>(bws + wlo * 16 + quad * 4);
    f32x4 cw = *reinterpret_cast<const f32x4*>(bws + 64 + wlo * 16 + quad * 4);
#pragma unroll
    for (int r = 0; r < 4; ++r) bv0[r] = cb[r] + t * cw[r];
    bv1 = *reinterpret_cast<const f32x4*>(bws + 128 + wlo * 16 + quad * 4);
  }

  bf16x8 wf2[2][2];
  f32x4  bv2[2];

  // ---------- L0: featT(global) or X(LDS) -> Y (wave: pts p0..p0+3, col wlo) ----------
  if constexpr (PRE) {
    const u16* fsrc = featT + (size_t)pair * 8192;
    bf16x8 a[4][2];
#pragma unroll
    for (int p = 0; p < 4; ++p)
#pragma unroll
      for (int ks = 0; ks < 2; ++ks)
        a[p][ks] = *reinterpret_cast<const bf16x8*>(
            fsrc + ((p0 + p) * 16 + l15) * 64 + (((ks * 4 + quad) ^ sw) * 8));
    // L2-layer weights: issue now, consumed two layers later (8 regs)
#pragma unroll
    for (int ot = 0; ot < 2; ++ot)
#pragma unroll
      for (int ks = 0; ks < 2; ++ks)
        wf2[ot][ks] = *reinterpret_cast<const bf16x8*>(
            wb + OFF_W2 + ((wave * 2 + ot) * 16 + l15) * 64 + ks * 32 + quad * 8);
    load_bv2(bv2, bws + 192);

    f32x4 accp[4];
#pragma unroll
    for (int p = 0; p < 4; ++p) accp[p] = bv0;
#pragma unroll
    for (int ks = 0; ks < 2; ++ks)
#pragma unroll
      for (int p = 0; p < 4; ++p) accp[p] = mf(wf0[ks], a[p][ks], accp[p]);
#pragma unroll
    for (int p = 0; p < 4; ++p)
      epilogue_sin<64>(accp[p], Y, (p0 + p) * 16 + l15, wlo * 2 + (quad >> 1), quad, sw);
  } else {
    // fallback: stage 128px into X, then classic LDS path
    {
      const int p  = tid & 127;    // 0..127
      const int gg = tid >> 7;     // 0..3
      const float* fbase = feat + (size_t)bq * 64 * kHW + hw0 + p;
#pragma unroll
      for (int j = 0; j < 2; ++j) {
        const int g = gg * 2 + j;
        float v[8];
#pragma unroll
        for (int e = 0; e < 8; ++e) v[e] = fbase[(size_t)(g * 8 + e) * kHW];
        uint4 pk;
        pk.x = pack2(v[0], v[1]);
        pk.y = pack2(v[2], v[3]);
        pk.z = pack2(v[4], v[5]);
        pk.w = pack2(v[6], v[7]);
        *reinterpret_cast<uint4*>(X + p * 64 + ((g ^ (p & 7)) * 8)) = pk;
      }
    }
    lds_barrier();
#pragma unroll
    for (int ot = 0; ot < 2; ++ot)
#pragma unroll
      for (int ks = 0; ks < 2; ++ks)
        wf2[ot][ks] = *reinterpret_cast<const bf16x8*>(
            wb + OFF_W2 + ((wave * 2 + ot) * 16 + l15) * 64 + ks * 32 + quad * 8);
    load_bv2(bv2, bws + 192);
#pragma unroll
    for (int p = 0; p < 4; ++p) {
      bf16x8 a[2];
      read_af2(a, X, p0 + p);
      f32x4 acc = bv0;
      acc = mf(wf0[0], a[0], acc); acc = mf(wf0[1], a[1], acc);
      epilogue_sin<64>(acc, Y, (p0 + p) * 16 + l15, wlo * 2 + (quad >> 1), quad, sw);
    }
  }
  lds_barrier();

  // ---------- L1: Y -> X ; issue FULL wf3 here (64 regs, window = L1+L2) ----------
  bf16x8 wf3[2][8];
  f32x4  bv3[2];
  {
    bf16x8 a[4][2];
    read_af2(a[0], Y, p0);
    read_af2(a[1], Y, p0 + 1);
    read_af2(a[2], Y, p0 + 2);
    read_af2(a[3], Y, p0 + 3);
    load_wf16(wf3, wb + OFF_W3);
    load_bv2(bv3, bws + 448);
    f32x4 accp[4];
#pragma unroll
    for (int p = 0; p < 4; ++p) accp[p] = bv1;
#pragma unroll
    for (int ks = 0; ks < 2; ++ks)
#pragma unroll
      for (int p = 0; p < 4; ++p) accp[p] = mf(wf1[ks], a[p][ks], accp[p]);
#pragma unroll
    for (int p = 0; p < 4; ++p)
      epilogue_sin<64>(accp[p], X, (p0 + p) * 16 + l15, wlo * 2 + (quad >> 1), quad, sw);
  }
  lds_barrier();

  // ---------- L2: X -> A32 (all 8 pts per wave, 2 out tiles) ----------
  {
    bf16x8 aA[2], aB[2];
    read_af2(aA, X, 0);
    read_af2(aB, X, 1);
    f32x4 accA[2], accB[2];
#pragma unroll
    for (int pp = 0; pp < 4; ++pp) {
#pragma unroll
      for (int ot = 0; ot < 2; ++ot) { accA[ot] = bv2[ot]; accB[ot] = bv2[ot]; }
#pragma unroll
      for (int ks = 0; ks < 2; ++ks)
#pragma unroll
        for (int ot = 0; ot < 2; ++ot) {
          accA[ot] = mf(wf2[ot][ks], aA[ks], accA[ot]);
          accB[ot] = mf(wf2[ot][ks], aB[ks], accB[ot]);
        }
      if (pp < 3) {
        read_af2(aA, X, pp * 2 + 2);
        read_af2(aB, X, pp * 2 + 3);
      }
      epi_pt2(accA, A32, pp * 2);
      epi_pt2(accB, A32, pp * 2 + 1);
    }
  }
  lds_barrier();

  // ---------- L3: A32 -> B32 ; mid-issue FULL wf4 (peak ~244 regs) ----------
  bf16x8 wf4[2][8];
  f32x4  bv4[2];
  {
    bf16x8 afA[8], afB[8];
    f32x4 accA[2], accB[2];
    read_af8(afA, A32, 0);
    read_af8(afB, A32, 1);
    // pair 0
    mfma_pair2(accA, accB, wf3, afA, afB, bv3);
    read_af8(afA, A32, 2);
    read_af8(afB, A32, 3);
    epi_pt2(accA, B32, 0);
    epi_pt2(accB, B32, 1);
    // pair 1
    mfma_pair2(accA, accB, wf3, afA, afB, bv3);
    read_af8(afA, A32, 4);
    read_af8(afB, A32, 5);
    // wf4 full prefetch: pinned so it can't hoist above pair-0/1 (reg peak).
    __builtin_amdgcn_sched_barrier(0);
    load_wf16(wf4, wb + OFF_W4);
    load_bv2(bv4, bws + 704);
    epi_pt2(accA, B32, 2);
    epi_pt2(accB, B32, 3);
    // pair 2
    mfma_pair2(accA, accB, wf3, afA, afB, bv3);
    read_af8(afA, A32, 6);
    read_af8(afB, A32, 7);
    epi_pt2(accA, B32, 4);
    epi_pt2(accB, B32, 5);
    // pair 3
    mfma_pair2(accA, accB, wf3, afA, afB, bv3);
    epi_pt2(accA, B32, 6);
    epi_pt2(accB, B32, 7);
  }
  lds_barrier();

  // ---------- L4: B32 -> A32 ; mid-issue wf5 (32 regs) ----------
  bf16x8 wf5[8];
  f32x4  bv5;
  {
    bf16x8 afA[8], afB[8];
    f32x4 accA[2], accB[2];
    read_af8(afA, B32, 0);
    read_af8(afB, B32, 1);
    // pair 0
    mfma_pair2(accA, accB, wf4, afA, afB, bv4);
    read_af8(afA, B32, 2);
    read_af8(afB, B32, 3);
    epi_pt2(accA, A32, 0);
    epi_pt2(accB, A32, 1);
    // pair 1
    mfma_pair2(accA, accB, wf4, afA, afB, bv4);
    read_af8(afA, B32, 4);
    read_af8(afB, B32, 5);
    __builtin_amdgcn_sched_barrier(0);
#pragma unroll
    for (int ks = 0; ks < 8; ++ks)  // wf5: 32 regs (col tile = wlo)
      wf5[ks] = *reinterpret_cast<const bf16x8*>(
          wb + OFF_W5 + (wlo * 16 + l15) * 256 + ks * 32 + quad * 8);
    bv5 = *reinterpret_cast<const f32x4*>(bws + 960 + wlo * 16 + quad * 4);
    epi_pt2(accA, A32, 2);
    epi_pt2(accB, A32, 3);
    // pair 2
    mfma_pair2(accA, accB, wf4, afA, afB, bv4);
    read_af8(afA, B32, 6);
    read_af8(afB, B32, 7);
    epi_pt2(accA, A32, 4);
    epi_pt2(accB, A32, 5);
    // pair 3
    mfma_pair2(accA, accB, wf4, afA, afB, bv4);
    epi_pt2(accA, A32, 6);
    epi_pt2(accB, A32, 7);
  }
  lds_barrier();

  // ---------- L5: A32 -> global (wave: pts p0..p0+3, col tile wlo) ----------
  {
    float* out_base = out + (size_t)(c * 2 + bq) * 64 * kHW + hw0;
    const int o = wlo * 16 + quad * 4;
    bf16x8 afA[8], afB[8];
    read_af8(afA, A32, p0);
    read_af8(afB, A32, p0 + 1);
#pragma unroll
    for (int pp = 0; pp < 2; ++pp) {
      f32x4 accA = bv5, accB = bv5;
#pragma unroll
      for (int ks = 0; ks < 8; ++ks) {
        accA = mf(wf5[ks], afA[ks], accA);
        accB = mf(wf5[ks], afB[ks], accB);
      }
      if (pp == 0) { read_af8(afA, A32, p0 + 2); read_af8(afB, A32, p0 + 3); }
      const int ptA = p0 + pp * 2, ptB = p0 + pp * 2 + 1;
      float* dstA = out_base + (size_t)o * kHW + (ptA * 16 + l15);
      float* dstB = out_base + (size_t)o * kHW + (ptB * 16 + l15);
#pragma unroll
      for (int r = 0; r < 4; ++r) dstA[(size_t)r * kHW] = accA[r];
#pragma unroll
      for (int r = 0; r < 4; ++r) dstB[(size_t)r * kHW] = accB[r];
    }
  }
}

extern "C" void kernel_launch(void* const* d_in, const int* in_sizes, int n_in,
                              void* d_out, int out_size, void* d_ws, size_t ws_size,
                              hipStream_t stream) {
  const float* feat  = (const float*)d_in[0];
  const float* times = (const float*)d_in[1];
  const float* w0 = (const float*)d_in[2];
  const float* b0 = (const float*)d_in[3];
  const float* w1 = (const float*)d_in[4];
  const float* b1 = (const float*)d_in[5];
  const float* w2 = (const float*)d_in[6];
  const float* b2 = (const float*)d_in[7];
  const float* w3 = (const float*)d_in[8];
  const float* b3 = (const float*)d_in[9];
  const float* w4 = (const float*)d_in[10];
  const float* b4 = (const float*)d_in[11];
  const float* w5 = (const float*)d_in[12];
  const float* b5 = (const float*)d_in[13];
  u16*   wb  = (u16*)d_ws;
  float* bws = (float*)((char*)d_ws + (size_t)W_TOTAL * 2);
  float* out = (float*)d_out;

  convert_weights<<<(W_TOTAL + B_TOTAL) / 256, 256, 0, stream>>>(
      w0, w1, w2, w3, w4, w5, b0, b1, b2, b3, b4, b5, wb, bws);

  if (ws_size >= WS_NEED) {
    u16* featT = (u16*)((char*)d_ws + FEAT_BYTE_OFF);
    convert_feat<<<1920, 256, 0, stream>>>(feat, featT);
    siren_main<true><<<2880, 512, 0, stream>>>(feat, times, wb, bws, featT, out);
  } else {
    siren_main<false><<<2880, 512, 0, stream>>>(feat, times, wb, bws, wb, out);
  }
}